// Round 14
// baseline (710.332 us; speedup 1.0000x reference)
//
#include <hip/hip_runtime.h>
#include <cstddef>
#include <cstdint>

#define N_NODES 100000
#define N_EDGES 3200000
#define D 256
#define BSHIFT 9                                // 512 rows per bucket
#define NBUCK ((N_NODES + (1 << BSHIFT) - 1) >> BSHIFT)  // 196
#define EPB 4096                                // edges per pass-1 block
#define CAP 20480                               // staging slots per bucket

typedef __attribute__((ext_vector_type(8))) short bf16x8;
typedef __attribute__((ext_vector_type(4))) float f32x4;
typedef unsigned int u32;

#define GLOAD16(gsrc, ldst)                                                      \
    __builtin_amdgcn_global_load_lds(                                            \
        (const __attribute__((address_space(1))) void*)(gsrc),                   \
        (__attribute__((address_space(3))) void*)(ldst), 16, 0, 0)

__device__ __forceinline__ ushort f2b(float f) {  // f32 -> bf16 RNE
    unsigned u = __float_as_uint(f);
    return (ushort)((u + 0x7fffu + ((u >> 16) & 1u)) >> 16);
}

// ---------------- bucket cursor init ----------------
__global__ void cursorinit_kernel(int* __restrict__ bucket_cursor) {
    int b = blockIdx.x * 256 + threadIdx.x;
    if (b < NBUCK) bucket_cursor[b] = b * CAP;
}

// ---------------- binned scatter pass 1 ----------------
__global__ __launch_bounds__(256) void binpass1_kernel(const int* __restrict__ erow,
                                                       const int* __restrict__ ecol,
                                                       const float* __restrict__ evalv,
                                                       int* __restrict__ bucket_cursor,
                                                       int2* __restrict__ staging) {
    __shared__ int cnt[NBUCK];
    __shared__ int lstart[NBUCK];
    __shared__ int gbase[NBUCK];
    __shared__ int wtot[4];
    __shared__ int woff[4];
    __shared__ int2 lcv[EPB];            // 32 KB
    __shared__ unsigned char lbb[EPB];   // 4 KB
    const int tid = threadIdx.x;
    const size_t base = (size_t)blockIdx.x * EPB;
    for (int b = tid; b < NBUCK; b += 256) cnt[b] = 0;
    __syncthreads();
    int bb[16];
    int2 pcv[16];
    int loff[16];
#pragma unroll
    for (int i = 0; i < 16; ++i) {
        size_t e = base + (size_t)i * 256 + tid;
        if (e < N_EDGES) {
            int r = erow[e];
            int b = r >> BSHIFT;
            bb[i] = b;
            pcv[i] = make_int2(ecol[e] | ((r & ((1 << BSHIFT) - 1)) << 17),
                               __float_as_int(evalv[e]));
            loff[i] = atomicAdd(&cnt[b], 1);
        } else {
            bb[i] = -1;
        }
    }
    __syncthreads();
    {
        int b = tid;
        int v = (b < NBUCK) ? cnt[b] : 0;
        int lane = tid & 63, wv = tid >> 6;
        int inc = v;
#pragma unroll
        for (int off = 1; off < 64; off <<= 1) {
            int u = __shfl_up(inc, off, 64);
            if (lane >= off) inc += u;
        }
        if (lane == 63) wtot[wv] = inc;
        __syncthreads();
        if (tid == 0) {
            int run = 0;
#pragma unroll
            for (int w = 0; w < 4; ++w) { woff[w] = run; run += wtot[w]; }
        }
        __syncthreads();
        int exc = woff[wv] + inc - v;
        if (b < NBUCK) {
            lstart[b] = exc;
            if (v > 0) gbase[b] = atomicAdd(&bucket_cursor[b], v);
        }
    }
    __syncthreads();
#pragma unroll
    for (int i = 0; i < 16; ++i) {
        if (bb[i] >= 0) {
            int p = lstart[bb[i]] + loff[i];
            lcv[p] = pcv[i];
            lbb[p] = (unsigned char)bb[i];
        }
    }
    __syncthreads();
    const int total = lstart[NBUCK - 1] + cnt[NBUCK - 1];
    for (int p = tid; p < total; p += 256) {
        int b = lbb[p];
        int g = gbase[b] + (p - lstart[b]);
        staging[g] = lcv[p];
    }
}

// ---------------- binned scatter pass 2: count+scan in LDS, emit rowrange --------
__global__ __launch_bounds__(256) void binpass2_kernel(const int* __restrict__ bucket_cursor,
                                                       const int2* __restrict__ staging,
                                                       int2* __restrict__ cedge,
                                                       int2* __restrict__ rowrange) {
    __shared__ int cnt[1 << BSHIFT];
    __shared__ int scur[1 << BSHIFT];
    __shared__ int wtot[4];
    __shared__ int woff[4];
    const int b   = blockIdx.x;
    const int tid = threadIdx.x;
    const int base = b * CAP;
    const int hi   = bucket_cursor[b];
    for (int i = tid; i < (1 << BSHIFT); i += 256) cnt[i] = 0;
    __syncthreads();
    for (int k = base + tid; k < hi; k += 256)
        atomicAdd(&cnt[((u32)staging[k].x) >> 17], 1);
    __syncthreads();
    int v0 = cnt[2 * tid];
    int v1 = cnt[2 * tid + 1];
    int s = v0 + v1;
    int lane = tid & 63, wv = tid >> 6;
    int inc = s;
#pragma unroll
    for (int off = 1; off < 64; off <<= 1) {
        int u = __shfl_up(inc, off, 64);
        if (lane >= off) inc += u;
    }
    if (lane == 63) wtot[wv] = inc;
    __syncthreads();
    if (tid == 0) {
        int run = 0;
#pragma unroll
        for (int w = 0; w < 4; ++w) { woff[w] = run; run += wtot[w]; }
    }
    __syncthreads();
    int exc = woff[wv] + inc - s;
    int g0 = base + exc;
    scur[2 * tid]     = g0;
    scur[2 * tid + 1] = g0 + v0;
    const int r0 = b << BSHIFT;
    int r = r0 + 2 * tid;
    if (r < N_NODES)     rowrange[r]     = make_int2(g0, g0 + v0);
    if (r + 1 < N_NODES) rowrange[r + 1] = make_int2(g0 + v0, g0 + v0 + v1);
    __syncthreads();
    for (int k = base + tid; k < hi; k += 256) {
        int2 e = staging[k];
        int rloc = ((u32)e.x) >> 17;
        int pos = atomicAdd(&scur[rloc], 1);
        cedge[pos] = make_int2(e.x & 0x1FFFF, e.y);
    }
}

// ---------------- f32 -> bf16 elementwise ----------------
__global__ __launch_bounds__(256) void cvt_kernel(const float* __restrict__ in,
                                                  ushort* __restrict__ out, int n4) {
    int i = blockIdx.x * 256 + threadIdx.x;
    if (i < n4) {
        float4 v = ((const float4*)in)[i];
        uint2 p;
        p.x = (unsigned)f2b(v.x) | ((unsigned)f2b(v.y) << 16);
        p.y = (unsigned)f2b(v.z) | ((unsigned)f2b(v.w) << 16);
        ((uint2*)out)[i] = p;
    }
}

// ---------------- W [512][256] f32 -> swizzled Wt bf16 ---------------------------
__global__ __launch_bounds__(256) void wtrans_kernel(const float* __restrict__ W1,
                                                     const float* __restrict__ Wout,
                                                     ushort* __restrict__ W1sz,
                                                     ushort* __restrict__ Woutsz) {
    int t = blockIdx.x * 256 + threadIdx.x;       // 0..262143
    const float* W = (t < 131072) ? W1 : Wout;
    ushort* Wsz    = (t < 131072) ? W1sz : Woutsz;
    int u = t & 131071;
    int j = u & 255;
    int k = u >> 8;
    int dst = j * 512 + ((((k >> 3) ^ (j & 63)) << 3) | (k & 7));
    Wsz[dst] = f2b(W[(size_t)k * 256 + j]);
}

// ---------------- CSR SpMM, D-split half pass: one wave per node, 128 cols -------
// Each launch gathers only a 128-col half of the table (25.6 MB working set
// ~ aggregate L2) -> higher L2 hit rate than full-row gather (51.2 MB WS).
// Lane reads one uint (2 bf16) per edge at h[col*256 + half*128 + lane*2].
__global__ __launch_bounds__(256) void spmm_half_kernel(const int2* __restrict__ rowrange,
                                                        const int2* __restrict__ cedge,
                                                        const ushort* __restrict__ h,
                                                        ushort* __restrict__ outb,
                                                        int half) {
    const int node = (blockIdx.x << 2) + (threadIdx.x >> 6);
    const int lane = threadIdx.x & 63;
    const ushort* __restrict__ hh = h + half * 128;   // half-selected col base
    int2 rr = rowrange[node];
    int k = rr.x;
    const int end = rr.y;
    float a0 = 0.f, a1 = 0.f;
#define EDGE_FMA(e, d)                                              \
    {                                                               \
        float v = __int_as_float((e).y);                            \
        a0 = fmaf(v, __uint_as_float((d) << 16), a0);               \
        a1 = fmaf(v, __uint_as_float((d) & 0xffff0000u), a1);       \
    }
    for (; k + 4 <= end; k += 4) {
        int2 e0 = cedge[k];
        int2 e1 = cedge[k + 1];
        int2 e2 = cedge[k + 2];
        int2 e3 = cedge[k + 3];
        u32 d0 = *(const u32*)(hh + (size_t)e0.x * 256 + lane * 2);
        u32 d1 = *(const u32*)(hh + (size_t)e1.x * 256 + lane * 2);
        u32 d2 = *(const u32*)(hh + (size_t)e2.x * 256 + lane * 2);
        u32 d3 = *(const u32*)(hh + (size_t)e3.x * 256 + lane * 2);
        EDGE_FMA(e0, d0)
        EDGE_FMA(e1, d1)
        EDGE_FMA(e2, d2)
        EDGE_FMA(e3, d3)
    }
    for (; k < end; ++k) {
        int2 e = cedge[k];
        u32 d = *(const u32*)(hh + (size_t)e.x * 256 + lane * 2);
        EDGE_FMA(e, d)
    }
#undef EDGE_FMA
    u32 p = (u32)f2b(a0) | ((u32)f2b(a1) << 16);
    ((u32*)outb)[(size_t)node * 128 + half * 64 + lane] = p;
}

// ---------------- MFMA concat-GEMM: B-resident LDS, barrier-free K loop ----------
template <bool OUT_BF16>
__global__ __launch_bounds__(512, 2) void gemm_mfma_kernel(const ushort* __restrict__ A1,
                                                           const ushort* __restrict__ A2,
                                                           const ushort* __restrict__ Wsz,
                                                           const float* __restrict__ bias,
                                                           void* __restrict__ outp) {
    __shared__ __align__(16) char lds[163840];  // B 0..131071, A rings 131072..163839
    const int tid  = threadIdx.x;
    const int wid  = tid >> 6;                  // 0..7
    const int lane = tid & 63;
    const int lr   = lane & 15;
    const int g    = lane >> 4;
    const int bm   = blockIdx.x * 128;
    const int c0   = blockIdx.y * 128;
    char* const ldsA = lds + 131072 + wid * 4096;

    int arow = bm + wid * 16 + (lane >> 2);
    if (arow >= N_NODES) arow = N_NODES - 1;    // clamp; stores guarded
    const int acol = (lane & 3) * 8;

#define STAGE_A(tt)                                                              \
    {                                                                            \
        const ushort* As_ = ((tt) < 8) ? A1 : A2;                                \
        GLOAD16(As_ + (size_t)arow * 256 + ((tt) & 7) * 32 + acol,               \
                ldsA + ((tt) & 3) * 1024);                                       \
    }

    int jbyte[8], jx[8];
#pragma unroll
    for (int cf = 0; cf < 8; ++cf) {
        int jl = cf * 16 + lr;
        jbyte[cf] = jl * 1024;
        jx[cf] = jl & 63;
    }

#pragma unroll
    for (int q = 0; q < 16; ++q)
        GLOAD16(Wsz + (size_t)c0 * 512 + (wid * 16 + q) * 512 + lane * 8,
                lds + (wid * 16 + q) * 1024);
    STAGE_A(0)
    STAGE_A(1)
    STAGE_A(2)
    asm volatile("s_waitcnt vmcnt(2)" ::: "memory");  // B + A(0) done
    __builtin_amdgcn_sched_barrier(0);
    __builtin_amdgcn_s_barrier();                     // all waves' B slices ready

    f32x4 acc[8];
#pragma unroll
    for (int cf = 0; cf < 8; ++cf) acc[cf] = (f32x4){0.f, 0.f, 0.f, 0.f};

#pragma unroll 1
    for (int t = 0; t < 16; ++t) {
        if (t < 13) {
            STAGE_A(t + 3)
            asm volatile("s_waitcnt vmcnt(3)" ::: "memory");
        } else if (t == 13) {
            asm volatile("s_waitcnt vmcnt(2)" ::: "memory");
        } else if (t == 14) {
            asm volatile("s_waitcnt vmcnt(1)" ::: "memory");
        } else {
            asm volatile("s_waitcnt vmcnt(0)" ::: "memory");
        }
        __builtin_amdgcn_sched_barrier(0);
        const char* Ab = ldsA + (t & 3) * 1024;
        bf16x8 af = *(const bf16x8*)(Ab + lr * 64 + g * 16);
        const int cbase = t * 4 + g;  // k-chunk index 0..63
#pragma unroll
        for (int cf = 0; cf < 8; ++cf) {
            bf16x8 bf_ = *(const bf16x8*)(lds + jbyte[cf] + ((cbase ^ jx[cf]) << 4));
            acc[cf] = __builtin_amdgcn_mfma_f32_16x16x32_bf16(af, bf_, acc[cf], 0, 0, 0);
        }
    }
#undef STAGE_A

    float bv[8];
#pragma unroll
    for (int cf = 0; cf < 8; ++cf) bv[cf] = bias[c0 + cf * 16 + lr];

    if (!OUT_BF16) {
        float* out = (float*)outp;
#pragma unroll
        for (int reg = 0; reg < 4; ++reg) {
            int row = bm + wid * 16 + g * 4 + reg;
            if (row < N_NODES) {
#pragma unroll
                for (int cf = 0; cf < 8; ++cf)
                    out[(size_t)row * 256 + c0 + cf * 16 + lr] = acc[cf][reg] + bv[cf];
            }
        }
    } else {
        __builtin_amdgcn_s_barrier();             // all waves done reading B
        ushort* out = (ushort*)outp;
        float (*L)[132] = (float(*)[132])(lds + wid * 16384);
#pragma unroll
        for (int cf = 0; cf < 8; ++cf)
#pragma unroll
            for (int reg = 0; reg < 4; ++reg)
                L[g * 4 + reg][cf * 16 + lr] = fmaxf(acc[cf][reg] + bv[cf], 0.f);
        asm volatile("s_waitcnt lgkmcnt(0)" ::: "memory");
        __builtin_amdgcn_sched_barrier(0);
        const int r  = lane >> 2;                 // 0..15
        const int cq = lane & 3;
        const int grow = bm + wid * 16 + r;
        if (grow < N_NODES) {
#pragma unroll
            for (int q = 0; q < 4; ++q) {
                int col = q * 32 + cq * 8;
                float4 u0 = *(const float4*)&L[r][col];
                float4 u1 = *(const float4*)&L[r][col + 4];
                uint4 w4;
                w4.x = (unsigned)f2b(u0.x) | ((unsigned)f2b(u0.y) << 16);
                w4.y = (unsigned)f2b(u0.z) | ((unsigned)f2b(u0.w) << 16);
                w4.z = (unsigned)f2b(u1.x) | ((unsigned)f2b(u1.y) << 16);
                w4.w = (unsigned)f2b(u1.z) | ((unsigned)f2b(u1.w) << 16);
                *(uint4*)&out[(size_t)grow * 256 + c0 + col] = w4;
            }
        }
    }
}

extern "C" void kernel_launch(void* const* d_in, const int* in_sizes, int n_in,
                              void* d_out, int out_size, void* d_ws, size_t ws_size,
                              hipStream_t stream) {
    const float* x     = (const float*)d_in[0];
    const int*   erow  = (const int*)d_in[1];
    const int*   ecol  = (const int*)d_in[2];
    const float* evalv = (const float*)d_in[3];
    const float* W1    = (const float*)d_in[4];
    const float* b1    = (const float*)d_in[5];
    const float* Wout  = (const float*)d_in[6];
    const float* bout  = (const float*)d_in[7];
    float* out = (float*)d_out;

    char* ws = (char*)d_ws;
    size_t off = 0;
    auto alloc = [&](size_t bytes) -> void* {
        void* p = ws + off;
        off += (bytes + 255) & ~(size_t)255;
        return p;
    };
    ushort* xb       = (ushort*)alloc((size_t)N_NODES * D * 2);     // 51.2 MB
    ushort* h1b      = (ushort*)alloc((size_t)N_NODES * D * 2);     // 51.2 MB
    ushort* neighb   = (ushort*)alloc((size_t)N_NODES * D * 2);     // 51.2 MB
    ushort* W1sz     = (ushort*)alloc((size_t)512 * 256 * 2);
    ushort* Woutsz   = (ushort*)alloc((size_t)512 * 256 * 2);
    int*    bcursor  = (int*)alloc((size_t)NBUCK * sizeof(int));
    int2*   rowrange = (int2*)alloc((size_t)N_NODES * sizeof(int2));      // 0.8 MB
    int2*   staging  = (int2*)alloc((size_t)NBUCK * CAP * sizeof(int2));  // 32.1 MB
    int2*   cedge    = (int2*)alloc((size_t)NBUCK * CAP * sizeof(int2));  // 32.1 MB

    // CSR build
    cursorinit_kernel<<<1, 256, 0, stream>>>(bcursor);
    binpass1_kernel<<<(N_EDGES + EPB - 1) / EPB, 256, 0, stream>>>(erow, ecol, evalv,
                                                                   bcursor, staging);
    binpass2_kernel<<<NBUCK, 256, 0, stream>>>(bcursor, staging, cedge, rowrange);

    // converts
    cvt_kernel<<<(N_NODES * D / 4 + 255) / 256, 256, 0, stream>>>(x, xb, N_NODES * D / 4);
    wtrans_kernel<<<1024, 256, 0, stream>>>(W1, Wout, W1sz, Woutsz);

    dim3 ggrid((N_NODES + 127) / 128, 2);  // 782 x 2
    const int sgrid = N_NODES / 4;
    // layer 1 (spmm as two sequential D-half passes)
    spmm_half_kernel<<<sgrid, 256, 0, stream>>>(rowrange, cedge, xb, neighb, 0);
    spmm_half_kernel<<<sgrid, 256, 0, stream>>>(rowrange, cedge, xb, neighb, 1);
    gemm_mfma_kernel<true><<<ggrid, 512, 0, stream>>>(xb, neighb, W1sz, b1, h1b);
    // layer 2
    spmm_half_kernel<<<sgrid, 256, 0, stream>>>(rowrange, cedge, h1b, neighb, 0);
    spmm_half_kernel<<<sgrid, 256, 0, stream>>>(rowrange, cedge, h1b, neighb, 1);
    gemm_mfma_kernel<false><<<ggrid, 512, 0, stream>>>(h1b, neighb, Woutsz, bout, out);
}

// Round 15
// 669.350 us; speedup vs baseline: 1.0612x; 1.0612x over previous
//
#include <hip/hip_runtime.h>
#include <cstddef>
#include <cstdint>

#define N_NODES 100000
#define N_EDGES 3200000
#define D 256
#define BSHIFT 9                                // 512 rows per bucket
#define NBUCK ((N_NODES + (1 << BSHIFT) - 1) >> BSHIFT)  // 196
#define EPB 4096                                // edges per pass-1 block
#define CAP 20480                               // staging slots per bucket

typedef __attribute__((ext_vector_type(8))) short bf16x8;
typedef __attribute__((ext_vector_type(4))) float f32x4;
typedef unsigned int u32;

#define GLOAD16(gsrc, ldst)                                                      \
    __builtin_amdgcn_global_load_lds(                                            \
        (const __attribute__((address_space(1))) void*)(gsrc),                   \
        (__attribute__((address_space(3))) void*)(ldst), 16, 0, 0)

__device__ __forceinline__ ushort f2b(float f) {  // f32 -> bf16 RNE
    unsigned u = __float_as_uint(f);
    return (ushort)((u + 0x7fffu + ((u >> 16) & 1u)) >> 16);
}

// ---------------- binned scatter pass 1 ----------------
__global__ __launch_bounds__(256) void binpass1_kernel(const int* __restrict__ erow,
                                                       const int* __restrict__ ecol,
                                                       const float* __restrict__ evalv,
                                                       int* __restrict__ bucket_cursor,
                                                       int2* __restrict__ staging) {
    __shared__ int cnt[NBUCK];
    __shared__ int lstart[NBUCK];
    __shared__ int gbase[NBUCK];
    __shared__ int wtot[4];
    __shared__ int woff[4];
    __shared__ int2 lcv[EPB];            // 32 KB
    __shared__ unsigned char lbb[EPB];   // 4 KB
    const int tid = threadIdx.x;
    const size_t base = (size_t)blockIdx.x * EPB;
    for (int b = tid; b < NBUCK; b += 256) cnt[b] = 0;
    __syncthreads();
    int bb[16];
    int2 pcv[16];
    int loff[16];
#pragma unroll
    for (int i = 0; i < 16; ++i) {
        size_t e = base + (size_t)i * 256 + tid;
        if (e < N_EDGES) {
            int r = erow[e];
            int b = r >> BSHIFT;
            bb[i] = b;
            pcv[i] = make_int2(ecol[e] | ((r & ((1 << BSHIFT) - 1)) << 17),
                               __float_as_int(evalv[e]));
            loff[i] = atomicAdd(&cnt[b], 1);
        } else {
            bb[i] = -1;
        }
    }
    __syncthreads();
    {
        int b = tid;
        int v = (b < NBUCK) ? cnt[b] : 0;
        int lane = tid & 63, wv = tid >> 6;
        int inc = v;
#pragma unroll
        for (int off = 1; off < 64; off <<= 1) {
            int u = __shfl_up(inc, off, 64);
            if (lane >= off) inc += u;
        }
        if (lane == 63) wtot[wv] = inc;
        __syncthreads();
        if (tid == 0) {
            int run = 0;
#pragma unroll
            for (int w = 0; w < 4; ++w) { woff[w] = run; run += wtot[w]; }
        }
        __syncthreads();
        int exc = woff[wv] + inc - v;
        if (b < NBUCK) {
            lstart[b] = exc;
            if (v > 0) gbase[b] = atomicAdd(&bucket_cursor[b], v);
        }
    }
    __syncthreads();
#pragma unroll
    for (int i = 0; i < 16; ++i) {
        if (bb[i] >= 0) {
            int p = lstart[bb[i]] + loff[i];
            lcv[p] = pcv[i];
            lbb[p] = (unsigned char)bb[i];
        }
    }
    __syncthreads();
    const int total = lstart[NBUCK - 1] + cnt[NBUCK - 1];
    for (int p = tid; p < total; p += 256) {
        int b = lbb[p];
        int g = gbase[b] + (p - lstart[b]);
        staging[g] = lcv[p];
    }
}

// ---------------- binned scatter pass 2: count+scan in LDS, emit rowrange --------
__global__ __launch_bounds__(256) void binpass2_kernel(const int* __restrict__ bucket_cursor,
                                                       const int2* __restrict__ staging,
                                                       int2* __restrict__ cedge,
                                                       int2* __restrict__ rowrange) {
    __shared__ int cnt[1 << BSHIFT];
    __shared__ int scur[1 << BSHIFT];
    __shared__ int wtot[4];
    __shared__ int woff[4];
    const int b   = blockIdx.x;
    const int tid = threadIdx.x;
    const int base = b * CAP;
    const int hi   = bucket_cursor[b];
    for (int i = tid; i < (1 << BSHIFT); i += 256) cnt[i] = 0;
    __syncthreads();
    for (int k = base + tid; k < hi; k += 256)
        atomicAdd(&cnt[((u32)staging[k].x) >> 17], 1);
    __syncthreads();
    int v0 = cnt[2 * tid];
    int v1 = cnt[2 * tid + 1];
    int s = v0 + v1;
    int lane = tid & 63, wv = tid >> 6;
    int inc = s;
#pragma unroll
    for (int off = 1; off < 64; off <<= 1) {
        int u = __shfl_up(inc, off, 64);
        if (lane >= off) inc += u;
    }
    if (lane == 63) wtot[wv] = inc;
    __syncthreads();
    if (tid == 0) {
        int run = 0;
#pragma unroll
        for (int w = 0; w < 4; ++w) { woff[w] = run; run += wtot[w]; }
    }
    __syncthreads();
    int exc = woff[wv] + inc - s;
    int g0 = base + exc;
    scur[2 * tid]     = g0;
    scur[2 * tid + 1] = g0 + v0;
    const int r0 = b << BSHIFT;
    int r = r0 + 2 * tid;
    if (r < N_NODES)     rowrange[r]     = make_int2(g0, g0 + v0);
    if (r + 1 < N_NODES) rowrange[r + 1] = make_int2(g0 + v0, g0 + v0 + v1);
    __syncthreads();
    for (int k = base + tid; k < hi; k += 256) {
        int2 e = staging[k];
        int rloc = ((u32)e.x) >> 17;
        int pos = atomicAdd(&scur[rloc], 1);
        cedge[pos] = make_int2(e.x & 0x1FFFF, e.y);
    }
}

// ---------------- f32 -> bf16 elementwise (+ folded bucket-cursor init) ----------
__global__ __launch_bounds__(256) void cvt_kernel(const float* __restrict__ in,
                                                  ushort* __restrict__ out, int n4,
                                                  int* __restrict__ bucket_cursor) {
    int i = blockIdx.x * 256 + threadIdx.x;
    if (blockIdx.x == 0 && threadIdx.x < NBUCK)
        bucket_cursor[threadIdx.x] = threadIdx.x * CAP;  // runs before binpass1 (stream order)
    if (i < n4) {
        float4 v = ((const float4*)in)[i];
        uint2 p;
        p.x = (unsigned)f2b(v.x) | ((unsigned)f2b(v.y) << 16);
        p.y = (unsigned)f2b(v.z) | ((unsigned)f2b(v.w) << 16);
        ((uint2*)out)[i] = p;
    }
}

// ---------------- W [512][256] f32 -> swizzled Wt bf16 ---------------------------
__global__ __launch_bounds__(256) void wtrans_kernel(const float* __restrict__ W1,
                                                     const float* __restrict__ Wout,
                                                     ushort* __restrict__ W1sz,
                                                     ushort* __restrict__ Woutsz) {
    int t = blockIdx.x * 256 + threadIdx.x;       // 0..262143
    const float* W = (t < 131072) ? W1 : Wout;
    ushort* Wsz    = (t < 131072) ? W1sz : Woutsz;
    int u = t & 131071;
    int j = u & 255;
    int k = u >> 8;
    int dst = j * 512 + ((((k >> 3) ^ (j & 63)) << 3) | (k & 7));
    Wsz[dst] = f2b(W[(size_t)k * 256 + j]);
}

// ---------------- CSR SpMM (bf16 features): one wave per node (R6-proven) ---------
__global__ __launch_bounds__(256) void spmm_kernel(const int2* __restrict__ rowrange,
                                                   const int2* __restrict__ cedge,
                                                   const ushort* __restrict__ h,
                                                   ushort* __restrict__ outb) {
    const int node = (blockIdx.x << 2) + (threadIdx.x >> 6);
    const int lane = threadIdx.x & 63;
    const uint2* __restrict__ h2 = (const uint2*)h;
    int2 rr = rowrange[node];
    int k = rr.x;
    const int end = rr.y;
    float a0 = 0.f, a1 = 0.f, a2 = 0.f, a3 = 0.f;
#define EDGE_FMA(e, d)                                              \
    {                                                               \
        float v = __int_as_float((e).y);                            \
        a0 = fmaf(v, __uint_as_float((d).x << 16), a0);             \
        a1 = fmaf(v, __uint_as_float((d).x & 0xffff0000u), a1);     \
        a2 = fmaf(v, __uint_as_float((d).y << 16), a2);             \
        a3 = fmaf(v, __uint_as_float((d).y & 0xffff0000u), a3);     \
    }
    for (; k + 4 <= end; k += 4) {
        int2 e0 = cedge[k];
        int2 e1 = cedge[k + 1];
        int2 e2 = cedge[k + 2];
        int2 e3 = cedge[k + 3];
        uint2 d0 = h2[(size_t)e0.x * 64 + lane];
        uint2 d1 = h2[(size_t)e1.x * 64 + lane];
        uint2 d2 = h2[(size_t)e2.x * 64 + lane];
        uint2 d3 = h2[(size_t)e3.x * 64 + lane];
        EDGE_FMA(e0, d0)
        EDGE_FMA(e1, d1)
        EDGE_FMA(e2, d2)
        EDGE_FMA(e3, d3)
    }
    for (; k < end; ++k) {
        int2 e = cedge[k];
        uint2 d = h2[(size_t)e.x * 64 + lane];
        EDGE_FMA(e, d)
    }
#undef EDGE_FMA
    uint2 p;
    p.x = (unsigned)f2b(a0) | ((unsigned)f2b(a1) << 16);
    p.y = (unsigned)f2b(a2) | ((unsigned)f2b(a3) << 16);
    ((uint2*)outb)[(size_t)node * 64 + lane] = p;
}

// ---------------- MFMA concat-GEMM: B-resident LDS, barrier-free K loop ----------
// Block = 128 rows x 128 cols, 512 threads (8 waves, 2/SIMD). B half (128KB,
// pre-swizzled in global) loaded ONCE; each wave owns 16 rows with a private
// 4-deep A ring (4x1KB) -> K-loop has NO barriers, only per-wave vmcnt(3).
template <bool OUT_BF16>
__global__ __launch_bounds__(512, 2) void gemm_mfma_kernel(const ushort* __restrict__ A1,
                                                           const ushort* __restrict__ A2,
                                                           const ushort* __restrict__ Wsz,
                                                           const float* __restrict__ bias,
                                                           void* __restrict__ outp) {
    __shared__ __align__(16) char lds[163840];  // B 0..131071, A rings 131072..163839
    const int tid  = threadIdx.x;
    const int wid  = tid >> 6;                  // 0..7
    const int lane = tid & 63;
    const int lr   = lane & 15;
    const int g    = lane >> 4;
    const int bm   = blockIdx.x * 128;
    const int c0   = blockIdx.y * 128;
    char* const ldsA = lds + 131072 + wid * 4096;

    int arow = bm + wid * 16 + (lane >> 2);
    if (arow >= N_NODES) arow = N_NODES - 1;    // clamp; stores guarded
    const int acol = (lane & 3) * 8;

#define STAGE_A(tt)                                                              \
    {                                                                            \
        const ushort* As_ = ((tt) < 8) ? A1 : A2;                                \
        GLOAD16(As_ + (size_t)arow * 256 + ((tt) & 7) * 32 + acol,               \
                ldsA + ((tt) & 3) * 1024);                                       \
    }

    int jbyte[8], jx[8];
#pragma unroll
    for (int cf = 0; cf < 8; ++cf) {
        int jl = cf * 16 + lr;
        jbyte[cf] = jl * 1024;
        jx[cf] = jl & 63;
    }

#pragma unroll
    for (int q = 0; q < 16; ++q)
        GLOAD16(Wsz + (size_t)c0 * 512 + (wid * 16 + q) * 512 + lane * 8,
                lds + (wid * 16 + q) * 1024);
    STAGE_A(0)
    STAGE_A(1)
    STAGE_A(2)
    asm volatile("s_waitcnt vmcnt(2)" ::: "memory");  // B + A(0) done
    __builtin_amdgcn_sched_barrier(0);
    __builtin_amdgcn_s_barrier();                     // all waves' B slices ready

    f32x4 acc[8];
#pragma unroll
    for (int cf = 0; cf < 8; ++cf) acc[cf] = (f32x4){0.f, 0.f, 0.f, 0.f};

#pragma unroll 1
    for (int t = 0; t < 16; ++t) {
        if (t < 13) {
            STAGE_A(t + 3)
            asm volatile("s_waitcnt vmcnt(3)" ::: "memory");
        } else if (t == 13) {
            asm volatile("s_waitcnt vmcnt(2)" ::: "memory");
        } else if (t == 14) {
            asm volatile("s_waitcnt vmcnt(1)" ::: "memory");
        } else {
            asm volatile("s_waitcnt vmcnt(0)" ::: "memory");
        }
        __builtin_amdgcn_sched_barrier(0);
        const char* Ab = ldsA + (t & 3) * 1024;
        bf16x8 af = *(const bf16x8*)(Ab + lr * 64 + g * 16);
        const int cbase = t * 4 + g;  // k-chunk index 0..63
#pragma unroll
        for (int cf = 0; cf < 8; ++cf) {
            bf16x8 bf_ = *(const bf16x8*)(lds + jbyte[cf] + ((cbase ^ jx[cf]) << 4));
            acc[cf] = __builtin_amdgcn_mfma_f32_16x16x32_bf16(af, bf_, acc[cf], 0, 0, 0);
        }
    }
#undef STAGE_A

    float bv[8];
#pragma unroll
    for (int cf = 0; cf < 8; ++cf) bv[cf] = bias[c0 + cf * 16 + lr];

    if (!OUT_BF16) {
        float* out = (float*)outp;
#pragma unroll
        for (int reg = 0; reg < 4; ++reg) {
            int row = bm + wid * 16 + g * 4 + reg;
            if (row < N_NODES) {
#pragma unroll
                for (int cf = 0; cf < 8; ++cf)
                    out[(size_t)row * 256 + c0 + cf * 16 + lr] = acc[cf][reg] + bv[cf];
            }
        }
    } else {
        __builtin_amdgcn_s_barrier();             // all waves done reading B
        ushort* out = (ushort*)outp;
        float (*L)[132] = (float(*)[132])(lds + wid * 16384);
#pragma unroll
        for (int cf = 0; cf < 8; ++cf)
#pragma unroll
            for (int reg = 0; reg < 4; ++reg)
                L[g * 4 + reg][cf * 16 + lr] = fmaxf(acc[cf][reg] + bv[cf], 0.f);
        asm volatile("s_waitcnt lgkmcnt(0)" ::: "memory");
        __builtin_amdgcn_sched_barrier(0);
        const int r  = lane >> 2;                 // 0..15
        const int cq = lane & 3;
        const int grow = bm + wid * 16 + r;
        if (grow < N_NODES) {
#pragma unroll
            for (int q = 0; q < 4; ++q) {
                int col = q * 32 + cq * 8;
                float4 u0 = *(const float4*)&L[r][col];
                float4 u1 = *(const float4*)&L[r][col + 4];
                uint4 w4;
                w4.x = (unsigned)f2b(u0.x) | ((unsigned)f2b(u0.y) << 16);
                w4.y = (unsigned)f2b(u0.z) | ((unsigned)f2b(u0.w) << 16);
                w4.z = (unsigned)f2b(u1.x) | ((unsigned)f2b(u1.y) << 16);
                w4.w = (unsigned)f2b(u1.z) | ((unsigned)f2b(u1.w) << 16);
                *(uint4*)&out[(size_t)grow * 256 + c0 + col] = w4;
            }
        }
    }
}

extern "C" void kernel_launch(void* const* d_in, const int* in_sizes, int n_in,
                              void* d_out, int out_size, void* d_ws, size_t ws_size,
                              hipStream_t stream) {
    const float* x     = (const float*)d_in[0];
    const int*   erow  = (const int*)d_in[1];
    const int*   ecol  = (const int*)d_in[2];
    const float* evalv = (const float*)d_in[3];
    const float* W1    = (const float*)d_in[4];
    const float* b1    = (const float*)d_in[5];
    const float* Wout  = (const float*)d_in[6];
    const float* bout  = (const float*)d_in[7];
    float* out = (float*)d_out;

    char* ws = (char*)d_ws;
    size_t off = 0;
    auto alloc = [&](size_t bytes) -> void* {
        void* p = ws + off;
        off += (bytes + 255) & ~(size_t)255;
        return p;
    };
    ushort* xb       = (ushort*)alloc((size_t)N_NODES * D * 2);     // 51.2 MB
    ushort* h1b      = (ushort*)alloc((size_t)N_NODES * D * 2);     // 51.2 MB
    ushort* neighb   = (ushort*)alloc((size_t)N_NODES * D * 2);     // 51.2 MB
    ushort* W1sz     = (ushort*)alloc((size_t)512 * 256 * 2);
    ushort* Woutsz   = (ushort*)alloc((size_t)512 * 256 * 2);
    int*    bcursor  = (int*)alloc((size_t)NBUCK * sizeof(int));
    int2*   rowrange = (int2*)alloc((size_t)N_NODES * sizeof(int2));      // 0.8 MB
    int2*   staging  = (int2*)alloc((size_t)NBUCK * CAP * sizeof(int2));  // 32.1 MB
    int2*   cedge    = (int2*)alloc((size_t)NBUCK * CAP * sizeof(int2));  // 32.1 MB

    // converts first (cvt also initializes bcursor; stream order covers binpass1)
    cvt_kernel<<<(N_NODES * D / 4 + 255) / 256, 256, 0, stream>>>(x, xb, N_NODES * D / 4,
                                                                  bcursor);
    wtrans_kernel<<<1024, 256, 0, stream>>>(W1, Wout, W1sz, Woutsz);

    // CSR build
    binpass1_kernel<<<(N_EDGES + EPB - 1) / EPB, 256, 0, stream>>>(erow, ecol, evalv,
                                                                   bcursor, staging);
    binpass2_kernel<<<NBUCK, 256, 0, stream>>>(bcursor, staging, cedge, rowrange);

    dim3 ggrid((N_NODES + 127) / 128, 2);  // 782 x 2
    const int sgrid = N_NODES / 4;
    // layer 1
    spmm_kernel<<<sgrid, 256, 0, stream>>>(rowrange, cedge, xb, neighb);
    gemm_mfma_kernel<true><<<ggrid, 512, 0, stream>>>(xb, neighb, W1sz, b1, h1b);
    // layer 2
    spmm_kernel<<<sgrid, 256, 0, stream>>>(rowrange, cedge, h1b, neighb);
    gemm_mfma_kernel<false><<<ggrid, 512, 0, stream>>>(h1b, neighb, Woutsz, bout, out);
}

// Round 16
// 492.494 us; speedup vs baseline: 1.4423x; 1.3591x over previous
//
#include <hip/hip_runtime.h>
#include <cstddef>
#include <cstdint>

#define N_NODES 100000
#define N_EDGES 3200000
#define D 256
#define BSHIFT 9                                // 512 rows per bucket
#define NBUCK ((N_NODES + (1 << BSHIFT) - 1) >> BSHIFT)  // 196
#define EPB 4096                                // edges per pass-1 block
#define CAP 20480                               // staging slots per bucket

typedef __attribute__((ext_vector_type(8))) short bf16x8;
typedef __attribute__((ext_vector_type(4))) float f32x4;
typedef __attribute__((ext_vector_type(2))) float f32x2;
typedef unsigned int u32;

#if defined(__has_builtin)
#if __has_builtin(__builtin_amdgcn_cvt_pk_f32_fp8) && __has_builtin(__builtin_amdgcn_cvt_pk_fp8_f32)
#define FP8_BUILTINS 1
#endif
#endif
#ifndef FP8_BUILTINS
#include <hip/hip_fp8.h>
#endif

__device__ __forceinline__ void fp8x4_to_f32(u32 d, float* f) {
#ifdef FP8_BUILTINS
    f32x2 lo = __builtin_amdgcn_cvt_pk_f32_fp8(d, false);
    f32x2 hi = __builtin_amdgcn_cvt_pk_f32_fp8(d, true);
    f[0] = lo.x; f[1] = lo.y; f[2] = hi.x; f[3] = hi.y;
#else
    __hip_fp8_e4m3 t;
#pragma unroll
    for (int i = 0; i < 4; ++i) { t.__x = (unsigned char)((d >> (8 * i)) & 0xff); f[i] = (float)t; }
#endif
}

__device__ __forceinline__ u32 f32x4_to_fp8(float a, float b, float c, float d) {
#ifdef FP8_BUILTINS
    u32 q = __builtin_amdgcn_cvt_pk_fp8_f32(a, b, 0u, false);
    return __builtin_amdgcn_cvt_pk_fp8_f32(c, d, q, true);
#else
    return (u32)__hip_fp8_e4m3(a).__x | ((u32)__hip_fp8_e4m3(b).__x << 8) |
           ((u32)__hip_fp8_e4m3(c).__x << 16) | ((u32)__hip_fp8_e4m3(d).__x << 24);
#endif
}

#define GLOAD16(gsrc, ldst)                                                      \
    __builtin_amdgcn_global_load_lds(                                            \
        (const __attribute__((address_space(1))) void*)(gsrc),                   \
        (__attribute__((address_space(3))) void*)(ldst), 16, 0, 0)

__device__ __forceinline__ ushort f2b(float f) {  // f32 -> bf16 RNE
    unsigned u = __float_as_uint(f);
    return (ushort)((u + 0x7fffu + ((u >> 16) & 1u)) >> 16);
}

// ---------------- binned scatter pass 1 ----------------
__global__ __launch_bounds__(256) void binpass1_kernel(const int* __restrict__ erow,
                                                       const int* __restrict__ ecol,
                                                       const float* __restrict__ evalv,
                                                       int* __restrict__ bucket_cursor,
                                                       int2* __restrict__ staging) {
    __shared__ int cnt[NBUCK];
    __shared__ int lstart[NBUCK];
    __shared__ int gbase[NBUCK];
    __shared__ int wtot[4];
    __shared__ int woff[4];
    __shared__ int2 lcv[EPB];            // 32 KB
    __shared__ unsigned char lbb[EPB];   // 4 KB
    const int tid = threadIdx.x;
    const size_t base = (size_t)blockIdx.x * EPB;
    for (int b = tid; b < NBUCK; b += 256) cnt[b] = 0;
    __syncthreads();
    int bb[16];
    int2 pcv[16];
    int loff[16];
#pragma unroll
    for (int i = 0; i < 16; ++i) {
        size_t e = base + (size_t)i * 256 + tid;
        if (e < N_EDGES) {
            int r = erow[e];
            int b = r >> BSHIFT;
            bb[i] = b;
            pcv[i] = make_int2(ecol[e] | ((r & ((1 << BSHIFT) - 1)) << 17),
                               __float_as_int(evalv[e]));
            loff[i] = atomicAdd(&cnt[b], 1);
        } else {
            bb[i] = -1;
        }
    }
    __syncthreads();
    {
        int b = tid;
        int v = (b < NBUCK) ? cnt[b] : 0;
        int lane = tid & 63, wv = tid >> 6;
        int inc = v;
#pragma unroll
        for (int off = 1; off < 64; off <<= 1) {
            int u = __shfl_up(inc, off, 64);
            if (lane >= off) inc += u;
        }
        if (lane == 63) wtot[wv] = inc;
        __syncthreads();
        if (tid == 0) {
            int run = 0;
#pragma unroll
            for (int w = 0; w < 4; ++w) { woff[w] = run; run += wtot[w]; }
        }
        __syncthreads();
        int exc = woff[wv] + inc - v;
        if (b < NBUCK) {
            lstart[b] = exc;
            if (v > 0) gbase[b] = atomicAdd(&bucket_cursor[b], v);
        }
    }
    __syncthreads();
#pragma unroll
    for (int i = 0; i < 16; ++i) {
        if (bb[i] >= 0) {
            int p = lstart[bb[i]] + loff[i];
            lcv[p] = pcv[i];
            lbb[p] = (unsigned char)bb[i];
        }
    }
    __syncthreads();
    const int total = lstart[NBUCK - 1] + cnt[NBUCK - 1];
    for (int p = tid; p < total; p += 256) {
        int b = lbb[p];
        int g = gbase[b] + (p - lstart[b]);
        staging[g] = lcv[p];
    }
}

// ---------------- binned scatter pass 2: count+scan in LDS, emit rowrange --------
__global__ __launch_bounds__(256) void binpass2_kernel(const int* __restrict__ bucket_cursor,
                                                       const int2* __restrict__ staging,
                                                       int2* __restrict__ cedge,
                                                       int2* __restrict__ rowrange) {
    __shared__ int cnt[1 << BSHIFT];
    __shared__ int scur[1 << BSHIFT];
    __shared__ int wtot[4];
    __shared__ int woff[4];
    const int b   = blockIdx.x;
    const int tid = threadIdx.x;
    const int base = b * CAP;
    const int hi   = bucket_cursor[b];
    for (int i = tid; i < (1 << BSHIFT); i += 256) cnt[i] = 0;
    __syncthreads();
    for (int k = base + tid; k < hi; k += 256)
        atomicAdd(&cnt[((u32)staging[k].x) >> 17], 1);
    __syncthreads();
    int v0 = cnt[2 * tid];
    int v1 = cnt[2 * tid + 1];
    int s = v0 + v1;
    int lane = tid & 63, wv = tid >> 6;
    int inc = s;
#pragma unroll
    for (int off = 1; off < 64; off <<= 1) {
        int u = __shfl_up(inc, off, 64);
        if (lane >= off) inc += u;
    }
    if (lane == 63) wtot[wv] = inc;
    __syncthreads();
    if (tid == 0) {
        int run = 0;
#pragma unroll
        for (int w = 0; w < 4; ++w) { woff[w] = run; run += wtot[w]; }
    }
    __syncthreads();
    int exc = woff[wv] + inc - s;
    int g0 = base + exc;
    scur[2 * tid]     = g0;
    scur[2 * tid + 1] = g0 + v0;
    const int r0 = b << BSHIFT;
    int r = r0 + 2 * tid;
    if (r < N_NODES)     rowrange[r]     = make_int2(g0, g0 + v0);
    if (r + 1 < N_NODES) rowrange[r + 1] = make_int2(g0 + v0, g0 + v0 + v1);
    __syncthreads();
    for (int k = base + tid; k < hi; k += 256) {
        int2 e = staging[k];
        int rloc = ((u32)e.x) >> 17;
        int pos = atomicAdd(&scur[rloc], 1);
        cedge[pos] = make_int2(e.x & 0x1FFFF, e.y);
    }
}

// ---------------- f32 -> bf16 + fp8 (+ folded bucket-cursor init) ----------------
__global__ __launch_bounds__(256) void cvt_kernel(const float* __restrict__ in,
                                                  ushort* __restrict__ out, int n4,
                                                  int* __restrict__ bucket_cursor,
                                                  u32* __restrict__ outq) {
    int i = blockIdx.x * 256 + threadIdx.x;
    if (blockIdx.x == 0 && threadIdx.x < NBUCK)
        bucket_cursor[threadIdx.x] = threadIdx.x * CAP;  // runs before binpass1 (stream order)
    if (i < n4) {
        float4 v = ((const float4*)in)[i];
        uint2 p;
        p.x = (unsigned)f2b(v.x) | ((unsigned)f2b(v.y) << 16);
        p.y = (unsigned)f2b(v.z) | ((unsigned)f2b(v.w) << 16);
        ((uint2*)out)[i] = p;
        outq[i] = f32x4_to_fp8(v.x, v.y, v.z, v.w);
    }
}

// ---------------- W [512][256] f32 -> swizzled Wt bf16 ---------------------------
__global__ __launch_bounds__(256) void wtrans_kernel(const float* __restrict__ W1,
                                                     const float* __restrict__ Wout,
                                                     ushort* __restrict__ W1sz,
                                                     ushort* __restrict__ Woutsz) {
    int t = blockIdx.x * 256 + threadIdx.x;       // 0..262143
    const float* W = (t < 131072) ? W1 : Wout;
    ushort* Wsz    = (t < 131072) ? W1sz : Woutsz;
    int u = t & 131071;
    int j = u & 255;
    int k = u >> 8;
    int dst = j * 512 + ((((k >> 3) ^ (j & 63)) << 3) | (k & 7));
    Wsz[dst] = f2b(W[(size_t)k * 256 + j]);
}

// ---------------- CSR SpMM, fp8 gather table: one wave per node ------------------
// Gather table is fp8 e4m3 (row = 256 B = 2 cache lines, half of bf16) ->
// halves the random-fill traffic that equals spmm's duration. Lane reads one
// u32 (4 fp8 = cols 4l..4l+3), HW-converts, accumulates f32, stores bf16.
__global__ __launch_bounds__(256) void spmm_kernel(const int2* __restrict__ rowrange,
                                                   const int2* __restrict__ cedge,
                                                   const unsigned char* __restrict__ hq,
                                                   ushort* __restrict__ outb) {
    const int node = (blockIdx.x << 2) + (threadIdx.x >> 6);
    const int lane = threadIdx.x & 63;
    const u32* __restrict__ h1 = (const u32*)hq;  // row = 64 u32
    int2 rr = rowrange[node];
    int k = rr.x;
    const int end = rr.y;
    float a0 = 0.f, a1 = 0.f, a2 = 0.f, a3 = 0.f;
#define EDGE_FMA(e, d)                                              \
    {                                                               \
        float v = __int_as_float((e).y);                            \
        float f[4];                                                 \
        fp8x4_to_f32((d), f);                                       \
        a0 = fmaf(v, f[0], a0); a1 = fmaf(v, f[1], a1);             \
        a2 = fmaf(v, f[2], a2); a3 = fmaf(v, f[3], a3);             \
    }
    for (; k + 4 <= end; k += 4) {
        int2 e0 = cedge[k];
        int2 e1 = cedge[k + 1];
        int2 e2 = cedge[k + 2];
        int2 e3 = cedge[k + 3];
        u32 d0 = h1[(size_t)e0.x * 64 + lane];
        u32 d1 = h1[(size_t)e1.x * 64 + lane];
        u32 d2 = h1[(size_t)e2.x * 64 + lane];
        u32 d3 = h1[(size_t)e3.x * 64 + lane];
        EDGE_FMA(e0, d0)
        EDGE_FMA(e1, d1)
        EDGE_FMA(e2, d2)
        EDGE_FMA(e3, d3)
    }
    for (; k < end; ++k) {
        int2 e = cedge[k];
        u32 d = h1[(size_t)e.x * 64 + lane];
        EDGE_FMA(e, d)
    }
#undef EDGE_FMA
    uint2 p;
    p.x = (unsigned)f2b(a0) | ((unsigned)f2b(a1) << 16);
    p.y = (unsigned)f2b(a2) | ((unsigned)f2b(a3) << 16);
    ((uint2*)outb)[(size_t)node * 64 + lane] = p;
}

// ---------------- MFMA concat-GEMM: B-resident LDS, barrier-free K loop ----------
// OUT_BF16 epilogue additionally writes the fp8 copy of h1 (spmm2's gather table).
template <bool OUT_BF16>
__global__ __launch_bounds__(512, 2) void gemm_mfma_kernel(const ushort* __restrict__ A1,
                                                           const ushort* __restrict__ A2,
                                                           const ushort* __restrict__ Wsz,
                                                           const float* __restrict__ bias,
                                                           void* __restrict__ outp,
                                                           unsigned char* __restrict__ outq) {
    __shared__ __align__(16) char lds[163840];  // B 0..131071, A rings 131072..163839
    const int tid  = threadIdx.x;
    const int wid  = tid >> 6;                  // 0..7
    const int lane = tid & 63;
    const int lr   = lane & 15;
    const int g    = lane >> 4;
    const int bm   = blockIdx.x * 128;
    const int c0   = blockIdx.y * 128;
    char* const ldsA = lds + 131072 + wid * 4096;

    int arow = bm + wid * 16 + (lane >> 2);
    if (arow >= N_NODES) arow = N_NODES - 1;    // clamp; stores guarded
    const int acol = (lane & 3) * 8;

#define STAGE_A(tt)                                                              \
    {                                                                            \
        const ushort* As_ = ((tt) < 8) ? A1 : A2;                                \
        GLOAD16(As_ + (size_t)arow * 256 + ((tt) & 7) * 32 + acol,               \
                ldsA + ((tt) & 3) * 1024);                                       \
    }

    int jbyte[8], jx[8];
#pragma unroll
    for (int cf = 0; cf < 8; ++cf) {
        int jl = cf * 16 + lr;
        jbyte[cf] = jl * 1024;
        jx[cf] = jl & 63;
    }

#pragma unroll
    for (int q = 0; q < 16; ++q)
        GLOAD16(Wsz + (size_t)c0 * 512 + (wid * 16 + q) * 512 + lane * 8,
                lds + (wid * 16 + q) * 1024);
    STAGE_A(0)
    STAGE_A(1)
    STAGE_A(2)
    asm volatile("s_waitcnt vmcnt(2)" ::: "memory");  // B + A(0) done
    __builtin_amdgcn_sched_barrier(0);
    __builtin_amdgcn_s_barrier();                     // all waves' B slices ready

    f32x4 acc[8];
#pragma unroll
    for (int cf = 0; cf < 8; ++cf) acc[cf] = (f32x4){0.f, 0.f, 0.f, 0.f};

#pragma unroll 1
    for (int t = 0; t < 16; ++t) {
        if (t < 13) {
            STAGE_A(t + 3)
            asm volatile("s_waitcnt vmcnt(3)" ::: "memory");
        } else if (t == 13) {
            asm volatile("s_waitcnt vmcnt(2)" ::: "memory");
        } else if (t == 14) {
            asm volatile("s_waitcnt vmcnt(1)" ::: "memory");
        } else {
            asm volatile("s_waitcnt vmcnt(0)" ::: "memory");
        }
        __builtin_amdgcn_sched_barrier(0);
        const char* Ab = ldsA + (t & 3) * 1024;
        bf16x8 af = *(const bf16x8*)(Ab + lr * 64 + g * 16);
        const int cbase = t * 4 + g;  // k-chunk index 0..63
#pragma unroll
        for (int cf = 0; cf < 8; ++cf) {
            bf16x8 bf_ = *(const bf16x8*)(lds + jbyte[cf] + ((cbase ^ jx[cf]) << 4));
            acc[cf] = __builtin_amdgcn_mfma_f32_16x16x32_bf16(af, bf_, acc[cf], 0, 0, 0);
        }
    }
#undef STAGE_A

    float bv[8];
#pragma unroll
    for (int cf = 0; cf < 8; ++cf) bv[cf] = bias[c0 + cf * 16 + lr];

    if (!OUT_BF16) {
        float* out = (float*)outp;
#pragma unroll
        for (int reg = 0; reg < 4; ++reg) {
            int row = bm + wid * 16 + g * 4 + reg;
            if (row < N_NODES) {
#pragma unroll
                for (int cf = 0; cf < 8; ++cf)
                    out[(size_t)row * 256 + c0 + cf * 16 + lr] = acc[cf][reg] + bv[cf];
            }
        }
    } else {
        __builtin_amdgcn_s_barrier();             // all waves done reading B
        ushort* out = (ushort*)outp;
        float (*L)[132] = (float(*)[132])(lds + wid * 16384);
#pragma unroll
        for (int cf = 0; cf < 8; ++cf)
#pragma unroll
            for (int reg = 0; reg < 4; ++reg)
                L[g * 4 + reg][cf * 16 + lr] = fmaxf(acc[cf][reg] + bv[cf], 0.f);
        asm volatile("s_waitcnt lgkmcnt(0)" ::: "memory");
        __builtin_amdgcn_sched_barrier(0);
        const int r  = lane >> 2;                 // 0..15
        const int cq = lane & 3;
        const int grow = bm + wid * 16 + r;
        if (grow < N_NODES) {
#pragma unroll
            for (int q = 0; q < 4; ++q) {
                int col = q * 32 + cq * 8;
                float4 u0 = *(const float4*)&L[r][col];
                float4 u1 = *(const float4*)&L[r][col + 4];
                uint4 w4;
                w4.x = (unsigned)f2b(u0.x) | ((unsigned)f2b(u0.y) << 16);
                w4.y = (unsigned)f2b(u0.z) | ((unsigned)f2b(u0.w) << 16);
                w4.z = (unsigned)f2b(u1.x) | ((unsigned)f2b(u1.y) << 16);
                w4.w = (unsigned)f2b(u1.z) | ((unsigned)f2b(u1.w) << 16);
                *(uint4*)&out[(size_t)grow * 256 + c0 + col] = w4;
                uint2 q8;
                q8.x = f32x4_to_fp8(u0.x, u0.y, u0.z, u0.w);
                q8.y = f32x4_to_fp8(u1.x, u1.y, u1.z, u1.w);
                *(uint2*)&outq[(size_t)grow * 256 + c0 + col] = q8;
            }
        }
    }
}

extern "C" void kernel_launch(void* const* d_in, const int* in_sizes, int n_in,
                              void* d_out, int out_size, void* d_ws, size_t ws_size,
                              hipStream_t stream) {
    const float* x     = (const float*)d_in[0];
    const int*   erow  = (const int*)d_in[1];
    const int*   ecol  = (const int*)d_in[2];
    const float* evalv = (const float*)d_in[3];
    const float* W1    = (const float*)d_in[4];
    const float* b1    = (const float*)d_in[5];
    const float* Wout  = (const float*)d_in[6];
    const float* bout  = (const float*)d_in[7];
    float* out = (float*)d_out;

    char* ws = (char*)d_ws;
    size_t off = 0;
    auto alloc = [&](size_t bytes) -> void* {
        void* p = ws + off;
        off += (bytes + 255) & ~(size_t)255;
        return p;
    };
    ushort* xb       = (ushort*)alloc((size_t)N_NODES * D * 2);     // 51.2 MB
    ushort* h1b      = (ushort*)alloc((size_t)N_NODES * D * 2);     // 51.2 MB
    ushort* neighb   = (ushort*)alloc((size_t)N_NODES * D * 2);     // 51.2 MB
    unsigned char* xq  = (unsigned char*)alloc((size_t)N_NODES * D);  // 25.6 MB
    unsigned char* h1q = (unsigned char*)alloc((size_t)N_NODES * D);  // 25.6 MB
    ushort* W1sz     = (ushort*)alloc((size_t)512 * 256 * 2);
    ushort* Woutsz   = (ushort*)alloc((size_t)512 * 256 * 2);
    int*    bcursor  = (int*)alloc((size_t)NBUCK * sizeof(int));
    int2*   rowrange = (int2*)alloc((size_t)N_NODES * sizeof(int2));      // 0.8 MB
    int2*   staging  = (int2*)alloc((size_t)NBUCK * CAP * sizeof(int2));  // 32.1 MB
    int2*   cedge    = (int2*)alloc((size_t)NBUCK * CAP * sizeof(int2));  // 32.1 MB

    // converts first (cvt also initializes bcursor; stream order covers binpass1)
    cvt_kernel<<<(N_NODES * D / 4 + 255) / 256, 256, 0, stream>>>(x, xb, N_NODES * D / 4,
                                                                  bcursor, (u32*)xq);
    wtrans_kernel<<<1024, 256, 0, stream>>>(W1, Wout, W1sz, Woutsz);

    // CSR build
    binpass1_kernel<<<(N_EDGES + EPB - 1) / EPB, 256, 0, stream>>>(erow, ecol, evalv,
                                                                   bcursor, staging);
    binpass2_kernel<<<NBUCK, 256, 0, stream>>>(bcursor, staging, cedge, rowrange);

    dim3 ggrid((N_NODES + 127) / 128, 2);  // 782 x 2
    const int sgrid = N_NODES / 4;
    // layer 1 (gather from fp8 x; GEMM A-inputs stay bf16)
    spmm_kernel<<<sgrid, 256, 0, stream>>>(rowrange, cedge, xq, neighb);
    gemm_mfma_kernel<true><<<ggrid, 512, 0, stream>>>(xb, neighb, W1sz, b1, h1b, h1q);
    // layer 2 (gather from fp8 h1)
    spmm_kernel<<<sgrid, 256, 0, stream>>>(rowrange, cedge, h1q, neighb);
    gemm_mfma_kernel<false><<<ggrid, 512, 0, stream>>>(h1b, neighb, Woutsz, bout, out, nullptr);
}

// Round 17
// 479.135 us; speedup vs baseline: 1.4825x; 1.0279x over previous
//
#include <hip/hip_runtime.h>
#include <cstddef>
#include <cstdint>

#define N_NODES 100000
#define N_EDGES 3200000
#define D 256
#define BSHIFT 9                                // 512 rows per bucket
#define NBUCK ((N_NODES + (1 << BSHIFT) - 1) >> BSHIFT)  // 196
#define EPB 4096                                // edges per pass-1 block
#define CAP 20480                               // staging slots per bucket

typedef __attribute__((ext_vector_type(8))) short bf16x8;
typedef __attribute__((ext_vector_type(4))) float f32x4;
typedef __attribute__((ext_vector_type(2))) float f32x2;
typedef unsigned int u32;

#if defined(__has_builtin)
#if __has_builtin(__builtin_amdgcn_cvt_pk_f32_fp8) && __has_builtin(__builtin_amdgcn_cvt_pk_fp8_f32)
#define FP8_BUILTINS 1
#endif
#endif
#ifndef FP8_BUILTINS
#include <hip/hip_fp8.h>
#endif

__device__ __forceinline__ void fp8x4_to_f32(u32 d, float* f) {
#ifdef FP8_BUILTINS
    f32x2 lo = __builtin_amdgcn_cvt_pk_f32_fp8(d, false);
    f32x2 hi = __builtin_amdgcn_cvt_pk_f32_fp8(d, true);
    f[0] = lo.x; f[1] = lo.y; f[2] = hi.x; f[3] = hi.y;
#else
    __hip_fp8_e4m3 t;
#pragma unroll
    for (int i = 0; i < 4; ++i) { t.__x = (unsigned char)((d >> (8 * i)) & 0xff); f[i] = (float)t; }
#endif
}

__device__ __forceinline__ u32 f32x4_to_fp8(float a, float b, float c, float d) {
#ifdef FP8_BUILTINS
    u32 q = __builtin_amdgcn_cvt_pk_fp8_f32(a, b, 0u, false);
    return __builtin_amdgcn_cvt_pk_fp8_f32(c, d, q, true);
#else
    return (u32)__hip_fp8_e4m3(a).__x | ((u32)__hip_fp8_e4m3(b).__x << 8) |
           ((u32)__hip_fp8_e4m3(c).__x << 16) | ((u32)__hip_fp8_e4m3(d).__x << 24);
#endif
}

#define GLOAD16(gsrc, ldst)                                                      \
    __builtin_amdgcn_global_load_lds(                                            \
        (const __attribute__((address_space(1))) void*)(gsrc),                   \
        (__attribute__((address_space(3))) void*)(ldst), 16, 0, 0)

__device__ __forceinline__ ushort f2b(float f) {  // f32 -> bf16 RNE
    unsigned u = __float_as_uint(f);
    return (ushort)((u + 0x7fffu + ((u >> 16) & 1u)) >> 16);
}

// ---------------- binned scatter pass 1 ----------------
__global__ __launch_bounds__(256) void binpass1_kernel(const int* __restrict__ erow,
                                                       const int* __restrict__ ecol,
                                                       const float* __restrict__ evalv,
                                                       int* __restrict__ bucket_cursor,
                                                       int2* __restrict__ staging) {
    __shared__ int cnt[NBUCK];
    __shared__ int lstart[NBUCK];
    __shared__ int gbase[NBUCK];
    __shared__ int wtot[4];
    __shared__ int woff[4];
    __shared__ int2 lcv[EPB];            // 32 KB
    __shared__ unsigned char lbb[EPB];   // 4 KB
    const int tid = threadIdx.x;
    const size_t base = (size_t)blockIdx.x * EPB;
    for (int b = tid; b < NBUCK; b += 256) cnt[b] = 0;
    __syncthreads();
    int bb[16];
    int2 pcv[16];
    int loff[16];
#pragma unroll
    for (int i = 0; i < 16; ++i) {
        size_t e = base + (size_t)i * 256 + tid;
        if (e < N_EDGES) {
            int r = erow[e];
            int b = r >> BSHIFT;
            bb[i] = b;
            pcv[i] = make_int2(ecol[e] | ((r & ((1 << BSHIFT) - 1)) << 17),
                               __float_as_int(evalv[e]));
            loff[i] = atomicAdd(&cnt[b], 1);
        } else {
            bb[i] = -1;
        }
    }
    __syncthreads();
    {
        int b = tid;
        int v = (b < NBUCK) ? cnt[b] : 0;
        int lane = tid & 63, wv = tid >> 6;
        int inc = v;
#pragma unroll
        for (int off = 1; off < 64; off <<= 1) {
            int u = __shfl_up(inc, off, 64);
            if (lane >= off) inc += u;
        }
        if (lane == 63) wtot[wv] = inc;
        __syncthreads();
        if (tid == 0) {
            int run = 0;
#pragma unroll
            for (int w = 0; w < 4; ++w) { woff[w] = run; run += wtot[w]; }
        }
        __syncthreads();
        int exc = woff[wv] + inc - v;
        if (b < NBUCK) {
            lstart[b] = exc;
            if (v > 0) gbase[b] = atomicAdd(&bucket_cursor[b], v);
        }
    }
    __syncthreads();
#pragma unroll
    for (int i = 0; i < 16; ++i) {
        if (bb[i] >= 0) {
            int p = lstart[bb[i]] + loff[i];
            lcv[p] = pcv[i];
            lbb[p] = (unsigned char)bb[i];
        }
    }
    __syncthreads();
    const int total = lstart[NBUCK - 1] + cnt[NBUCK - 1];
    for (int p = tid; p < total; p += 256) {
        int b = lbb[p];
        int g = gbase[b] + (p - lstart[b]);
        staging[g] = lcv[p];
    }
}

// ---------------- binned scatter pass 2: count+scan in LDS, emit rowrange --------
__global__ __launch_bounds__(256) void binpass2_kernel(const int* __restrict__ bucket_cursor,
                                                       const int2* __restrict__ staging,
                                                       int2* __restrict__ cedge,
                                                       int2* __restrict__ rowrange) {
    __shared__ int cnt[1 << BSHIFT];
    __shared__ int scur[1 << BSHIFT];
    __shared__ int wtot[4];
    __shared__ int woff[4];
    const int b   = blockIdx.x;
    const int tid = threadIdx.x;
    const int base = b * CAP;
    const int hi   = bucket_cursor[b];
    for (int i = tid; i < (1 << BSHIFT); i += 256) cnt[i] = 0;
    __syncthreads();
    for (int k = base + tid; k < hi; k += 256)
        atomicAdd(&cnt[((u32)staging[k].x) >> 17], 1);
    __syncthreads();
    int v0 = cnt[2 * tid];
    int v1 = cnt[2 * tid + 1];
    int s = v0 + v1;
    int lane = tid & 63, wv = tid >> 6;
    int inc = s;
#pragma unroll
    for (int off = 1; off < 64; off <<= 1) {
        int u = __shfl_up(inc, off, 64);
        if (lane >= off) inc += u;
    }
    if (lane == 63) wtot[wv] = inc;
    __syncthreads();
    if (tid == 0) {
        int run = 0;
#pragma unroll
        for (int w = 0; w < 4; ++w) { woff[w] = run; run += wtot[w]; }
    }
    __syncthreads();
    int exc = woff[wv] + inc - s;
    int g0 = base + exc;
    scur[2 * tid]     = g0;
    scur[2 * tid + 1] = g0 + v0;
    const int r0 = b << BSHIFT;
    int r = r0 + 2 * tid;
    if (r < N_NODES)     rowrange[r]     = make_int2(g0, g0 + v0);
    if (r + 1 < N_NODES) rowrange[r + 1] = make_int2(g0 + v0, g0 + v0 + v1);
    __syncthreads();
    for (int k = base + tid; k < hi; k += 256) {
        int2 e = staging[k];
        int rloc = ((u32)e.x) >> 17;
        int pos = atomicAdd(&scur[rloc], 1);
        cedge[pos] = make_int2(e.x & 0x1FFFF, e.y);
    }
}

// ---------------- f32 -> bf16 + fp8 (+ folded bucket-cursor init) ----------------
__global__ __launch_bounds__(256) void cvt_kernel(const float* __restrict__ in,
                                                  ushort* __restrict__ out, int n4,
                                                  int* __restrict__ bucket_cursor,
                                                  u32* __restrict__ outq) {
    int i = blockIdx.x * 256 + threadIdx.x;
    if (blockIdx.x == 0 && threadIdx.x < NBUCK)
        bucket_cursor[threadIdx.x] = threadIdx.x * CAP;  // runs before binpass1 (stream order)
    if (i < n4) {
        float4 v = ((const float4*)in)[i];
        uint2 p;
        p.x = (unsigned)f2b(v.x) | ((unsigned)f2b(v.y) << 16);
        p.y = (unsigned)f2b(v.z) | ((unsigned)f2b(v.w) << 16);
        ((uint2*)out)[i] = p;
        outq[i] = f32x4_to_fp8(v.x, v.y, v.z, v.w);
    }
}

// ---------------- W [512][256] f32 -> swizzled Wt bf16 ---------------------------
__global__ __launch_bounds__(256) void wtrans_kernel(const float* __restrict__ W1,
                                                     const float* __restrict__ Wout,
                                                     ushort* __restrict__ W1sz,
                                                     ushort* __restrict__ Woutsz) {
    int t = blockIdx.x * 256 + threadIdx.x;       // 0..262143
    const float* W = (t < 131072) ? W1 : Wout;
    ushort* Wsz    = (t < 131072) ? W1sz : Woutsz;
    int u = t & 131071;
    int j = u & 255;
    int k = u >> 8;
    int dst = j * 512 + ((((k >> 3) ^ (j & 63)) << 3) | (k & 7));
    Wsz[dst] = f2b(W[(size_t)k * 256 + j]);
}

// ---------------- CSR SpMM, fp8 gather table: one wave per node, unroll 8 --------
// fp8 rows are 256 B -> at unroll 4 only 1 KB in flight per wave (vs 2 KB for
// bf16), which dropped fill BW to 2.87 TB/s (MLP-limited). Unroll 8 restores
// 2 KB in flight; decode stays 2x cvt_pk + 4 fma per edge.
__global__ __launch_bounds__(256) void spmm_kernel(const int2* __restrict__ rowrange,
                                                   const int2* __restrict__ cedge,
                                                   const unsigned char* __restrict__ hq,
                                                   ushort* __restrict__ outb) {
    const int node = (blockIdx.x << 2) + (threadIdx.x >> 6);
    const int lane = threadIdx.x & 63;
    const u32* __restrict__ h1 = (const u32*)hq + lane;  // row = 64 u32
    int2 rr = rowrange[node];
    int k = rr.x;
    const int end = rr.y;
    float a0 = 0.f, a1 = 0.f, a2 = 0.f, a3 = 0.f;
#define EDGE_FMA(e, d)                                              \
    {                                                               \
        float v = __int_as_float((e).y);                            \
        float f[4];                                                 \
        fp8x4_to_f32((d), f);                                       \
        a0 = fmaf(v, f[0], a0); a1 = fmaf(v, f[1], a1);             \
        a2 = fmaf(v, f[2], a2); a3 = fmaf(v, f[3], a3);             \
    }
    for (; k + 8 <= end; k += 8) {
        int2 e[8];
#pragma unroll
        for (int i = 0; i < 8; ++i) e[i] = cedge[k + i];
        u32 d[8];
#pragma unroll
        for (int i = 0; i < 8; ++i) d[i] = h1[(u32)e[i].x * 64];
#pragma unroll
        for (int i = 0; i < 8; ++i) EDGE_FMA(e[i], d[i])
    }
    for (; k < end; ++k) {
        int2 e = cedge[k];
        u32 d = h1[(u32)e.x * 64];
        EDGE_FMA(e, d)
    }
#undef EDGE_FMA
    uint2 p;
    p.x = (unsigned)f2b(a0) | ((unsigned)f2b(a1) << 16);
    p.y = (unsigned)f2b(a2) | ((unsigned)f2b(a3) << 16);
    ((uint2*)outb)[(size_t)node * 64 + lane] = p;
}

// ---------------- MFMA concat-GEMM: B-resident LDS, barrier-free K loop ----------
// OUT_BF16 epilogue additionally writes the fp8 copy of h1 (spmm2's gather table).
template <bool OUT_BF16>
__global__ __launch_bounds__(512, 2) void gemm_mfma_kernel(const ushort* __restrict__ A1,
                                                           const ushort* __restrict__ A2,
                                                           const ushort* __restrict__ Wsz,
                                                           const float* __restrict__ bias,
                                                           void* __restrict__ outp,
                                                           unsigned char* __restrict__ outq) {
    __shared__ __align__(16) char lds[163840];  // B 0..131071, A rings 131072..163839
    const int tid  = threadIdx.x;
    const int wid  = tid >> 6;                  // 0..7
    const int lane = tid & 63;
    const int lr   = lane & 15;
    const int g    = lane >> 4;
    const int bm   = blockIdx.x * 128;
    const int c0   = blockIdx.y * 128;
    char* const ldsA = lds + 131072 + wid * 4096;

    int arow = bm + wid * 16 + (lane >> 2);
    if (arow >= N_NODES) arow = N_NODES - 1;    // clamp; stores guarded
    const int acol = (lane & 3) * 8;

#define STAGE_A(tt)                                                              \
    {                                                                            \
        const ushort* As_ = ((tt) < 8) ? A1 : A2;                                \
        GLOAD16(As_ + (size_t)arow * 256 + ((tt) & 7) * 32 + acol,               \
                ldsA + ((tt) & 3) * 1024);                                       \
    }

    int jbyte[8], jx[8];
#pragma unroll
    for (int cf = 0; cf < 8; ++cf) {
        int jl = cf * 16 + lr;
        jbyte[cf] = jl * 1024;
        jx[cf] = jl & 63;
    }

#pragma unroll
    for (int q = 0; q < 16; ++q)
        GLOAD16(Wsz + (size_t)c0 * 512 + (wid * 16 + q) * 512 + lane * 8,
                lds + (wid * 16 + q) * 1024);
    STAGE_A(0)
    STAGE_A(1)
    STAGE_A(2)
    asm volatile("s_waitcnt vmcnt(2)" ::: "memory");  // B + A(0) done
    __builtin_amdgcn_sched_barrier(0);
    __builtin_amdgcn_s_barrier();                     // all waves' B slices ready

    f32x4 acc[8];
#pragma unroll
    for (int cf = 0; cf < 8; ++cf) acc[cf] = (f32x4){0.f, 0.f, 0.f, 0.f};

#pragma unroll 1
    for (int t = 0; t < 16; ++t) {
        if (t < 13) {
            STAGE_A(t + 3)
            asm volatile("s_waitcnt vmcnt(3)" ::: "memory");
        } else if (t == 13) {
            asm volatile("s_waitcnt vmcnt(2)" ::: "memory");
        } else if (t == 14) {
            asm volatile("s_waitcnt vmcnt(1)" ::: "memory");
        } else {
            asm volatile("s_waitcnt vmcnt(0)" ::: "memory");
        }
        __builtin_amdgcn_sched_barrier(0);
        const char* Ab = ldsA + (t & 3) * 1024;
        bf16x8 af = *(const bf16x8*)(Ab + lr * 64 + g * 16);
        const int cbase = t * 4 + g;  // k-chunk index 0..63
#pragma unroll
        for (int cf = 0; cf < 8; ++cf) {
            bf16x8 bf_ = *(const bf16x8*)(lds + jbyte[cf] + ((cbase ^ jx[cf]) << 4));
            acc[cf] = __builtin_amdgcn_mfma_f32_16x16x32_bf16(af, bf_, acc[cf], 0, 0, 0);
        }
    }
#undef STAGE_A

    float bv[8];
#pragma unroll
    for (int cf = 0; cf < 8; ++cf) bv[cf] = bias[c0 + cf * 16 + lr];

    if (!OUT_BF16) {
        float* out = (float*)outp;
#pragma unroll
        for (int reg = 0; reg < 4; ++reg) {
            int row = bm + wid * 16 + g * 4 + reg;
            if (row < N_NODES) {
#pragma unroll
                for (int cf = 0; cf < 8; ++cf)
                    out[(size_t)row * 256 + c0 + cf * 16 + lr] = acc[cf][reg] + bv[cf];
            }
        }
    } else {
        __builtin_amdgcn_s_barrier();             // all waves done reading B
        ushort* out = (ushort*)outp;
        float (*L)[132] = (float(*)[132])(lds + wid * 16384);
#pragma unroll
        for (int cf = 0; cf < 8; ++cf)
#pragma unroll
            for (int reg = 0; reg < 4; ++reg)
                L[g * 4 + reg][cf * 16 + lr] = fmaxf(acc[cf][reg] + bv[cf], 0.f);
        asm volatile("s_waitcnt lgkmcnt(0)" ::: "memory");
        __builtin_amdgcn_sched_barrier(0);
        const int r  = lane >> 2;                 // 0..15
        const int cq = lane & 3;
        const int grow = bm + wid * 16 + r;
        if (grow < N_NODES) {
#pragma unroll
            for (int q = 0; q < 4; ++q) {
                int col = q * 32 + cq * 8;
                float4 u0 = *(const float4*)&L[r][col];
                float4 u1 = *(const float4*)&L[r][col + 4];
                uint4 w4;
                w4.x = (unsigned)f2b(u0.x) | ((unsigned)f2b(u0.y) << 16);
                w4.y = (unsigned)f2b(u0.z) | ((unsigned)f2b(u0.w) << 16);
                w4.z = (unsigned)f2b(u1.x) | ((unsigned)f2b(u1.y) << 16);
                w4.w = (unsigned)f2b(u1.z) | ((unsigned)f2b(u1.w) << 16);
                *(uint4*)&out[(size_t)grow * 256 + c0 + col] = w4;
                uint2 q8;
                q8.x = f32x4_to_fp8(u0.x, u0.y, u0.z, u0.w);
                q8.y = f32x4_to_fp8(u1.x, u1.y, u1.z, u1.w);
                *(uint2*)&outq[(size_t)grow * 256 + c0 + col] = q8;
            }
        }
    }
}

extern "C" void kernel_launch(void* const* d_in, const int* in_sizes, int n_in,
                              void* d_out, int out_size, void* d_ws, size_t ws_size,
                              hipStream_t stream) {
    const float* x     = (const float*)d_in[0];
    const int*   erow  = (const int*)d_in[1];
    const int*   ecol  = (const int*)d_in[2];
    const float* evalv = (const float*)d_in[3];
    const float* W1    = (const float*)d_in[4];
    const float* b1    = (const float*)d_in[5];
    const float* Wout  = (const float*)d_in[6];
    const float* bout  = (const float*)d_in[7];
    float* out = (float*)d_out;

    char* ws = (char*)d_ws;
    size_t off = 0;
    auto alloc = [&](size_t bytes) -> void* {
        void* p = ws + off;
        off += (bytes + 255) & ~(size_t)255;
        return p;
    };
    ushort* xb       = (ushort*)alloc((size_t)N_NODES * D * 2);     // 51.2 MB
    ushort* h1b      = (ushort*)alloc((size_t)N_NODES * D * 2);     // 51.2 MB
    ushort* neighb   = (ushort*)alloc((size_t)N_NODES * D * 2);     // 51.2 MB
    unsigned char* xq  = (unsigned char*)alloc((size_t)N_NODES * D);  // 25.6 MB
    unsigned char* h1q = (unsigned char*)alloc((size_t)N_NODES * D);  // 25.6 MB
    ushort* W1sz     = (ushort*)alloc((size_t)512 * 256 * 2);
    ushort* Woutsz   = (ushort*)alloc((size_t)512 * 256 * 2);
    int*    bcursor  = (int*)alloc((size_t)NBUCK * sizeof(int));
    int2*   rowrange = (int2*)alloc((size_t)N_NODES * sizeof(int2));      // 0.8 MB
    int2*   staging  = (int2*)alloc((size_t)NBUCK * CAP * sizeof(int2));  // 32.1 MB
    int2*   cedge    = (int2*)alloc((size_t)NBUCK * CAP * sizeof(int2));  // 32.1 MB

    // converts first (cvt also initializes bcursor; stream order covers binpass1)
    cvt_kernel<<<(N_NODES * D / 4 + 255) / 256, 256, 0, stream>>>(x, xb, N_NODES * D / 4,
                                                                  bcursor, (u32*)xq);
    wtrans_kernel<<<1024, 256, 0, stream>>>(W1, Wout, W1sz, Woutsz);

    // CSR build
    binpass1_kernel<<<(N_EDGES + EPB - 1) / EPB, 256, 0, stream>>>(erow, ecol, evalv,
                                                                   bcursor, staging);
    binpass2_kernel<<<NBUCK, 256, 0, stream>>>(bcursor, staging, cedge, rowrange);

    dim3 ggrid((N_NODES + 127) / 128, 2);  // 782 x 2
    const int sgrid = N_NODES / 4;
    // layer 1 (gather from fp8 x; GEMM A-inputs stay bf16)
    spmm_kernel<<<sgrid, 256, 0, stream>>>(rowrange, cedge, xq, neighb);
    gemm_mfma_kernel<true><<<ggrid, 512, 0, stream>>>(xb, neighb, W1sz, b1, h1b, h1q);
    // layer 2 (gather from fp8 h1)
    spmm_kernel<<<sgrid, 256, 0, stream>>>(rowrange, cedge, h1q, neighb);
    gemm_mfma_kernel<false><<<ggrid, 512, 0, stream>>>(h1b, neighb, Woutsz, bout, out, nullptr);
}

// Round 18
// 478.299 us; speedup vs baseline: 1.4851x; 1.0017x over previous
//
#include <hip/hip_runtime.h>
#include <cstddef>
#include <cstdint>

#define N_NODES 100000
#define N_EDGES 3200000
#define D 256
#define BSHIFT 9                                // 512 rows per bucket
#define NBUCK ((N_NODES + (1 << BSHIFT) - 1) >> BSHIFT)  // 196
#define EPB 4096                                // edges per pass-1 block
#define CAP 20480                               // staging slots per bucket

typedef __attribute__((ext_vector_type(8))) short bf16x8;
typedef __attribute__((ext_vector_type(4))) float f32x4;
typedef __attribute__((ext_vector_type(2))) float f32x2;
typedef unsigned int u32;

#if defined(__has_builtin)
#if __has_builtin(__builtin_amdgcn_cvt_pk_f32_fp8) && __has_builtin(__builtin_amdgcn_cvt_pk_fp8_f32)
#define FP8_BUILTINS 1
#endif
#endif
#ifndef FP8_BUILTINS
#include <hip/hip_fp8.h>
#endif

__device__ __forceinline__ void fp8x4_to_f32(u32 d, float* f) {
#ifdef FP8_BUILTINS
    f32x2 lo = __builtin_amdgcn_cvt_pk_f32_fp8(d, false);
    f32x2 hi = __builtin_amdgcn_cvt_pk_f32_fp8(d, true);
    f[0] = lo.x; f[1] = lo.y; f[2] = hi.x; f[3] = hi.y;
#else
    __hip_fp8_e4m3 t;
#pragma unroll
    for (int i = 0; i < 4; ++i) { t.__x = (unsigned char)((d >> (8 * i)) & 0xff); f[i] = (float)t; }
#endif
}

__device__ __forceinline__ u32 f32x4_to_fp8(float a, float b, float c, float d) {
#ifdef FP8_BUILTINS
    u32 q = __builtin_amdgcn_cvt_pk_fp8_f32(a, b, 0u, false);
    return __builtin_amdgcn_cvt_pk_fp8_f32(c, d, q, true);
#else
    return (u32)__hip_fp8_e4m3(a).__x | ((u32)__hip_fp8_e4m3(b).__x << 8) |
           ((u32)__hip_fp8_e4m3(c).__x << 16) | ((u32)__hip_fp8_e4m3(d).__x << 24);
#endif
}

#define GLOAD16(gsrc, ldst)                                                      \
    __builtin_amdgcn_global_load_lds(                                            \
        (const __attribute__((address_space(1))) void*)(gsrc),                   \
        (__attribute__((address_space(3))) void*)(ldst), 16, 0, 0)

__device__ __forceinline__ ushort f2b(float f) {  // f32 -> bf16 RNE
    unsigned u = __float_as_uint(f);
    return (ushort)((u + 0x7fffu + ((u >> 16) & 1u)) >> 16);
}

// ---------------- binned scatter pass 1 ----------------
__global__ __launch_bounds__(256) void binpass1_kernel(const int* __restrict__ erow,
                                                       const int* __restrict__ ecol,
                                                       const float* __restrict__ evalv,
                                                       int* __restrict__ bucket_cursor,
                                                       int2* __restrict__ staging) {
    __shared__ int cnt[NBUCK];
    __shared__ int lstart[NBUCK];
    __shared__ int gbase[NBUCK];
    __shared__ int wtot[4];
    __shared__ int woff[4];
    __shared__ int2 lcv[EPB];            // 32 KB
    __shared__ unsigned char lbb[EPB];   // 4 KB
    const int tid = threadIdx.x;
    const size_t base = (size_t)blockIdx.x * EPB;
    for (int b = tid; b < NBUCK; b += 256) cnt[b] = 0;
    __syncthreads();
    int bb[16];
    int2 pcv[16];
    int loff[16];
#pragma unroll
    for (int i = 0; i < 16; ++i) {
        size_t e = base + (size_t)i * 256 + tid;
        if (e < N_EDGES) {
            int r = erow[e];
            int b = r >> BSHIFT;
            bb[i] = b;
            pcv[i] = make_int2(ecol[e] | ((r & ((1 << BSHIFT) - 1)) << 17),
                               __float_as_int(evalv[e]));
            loff[i] = atomicAdd(&cnt[b], 1);
        } else {
            bb[i] = -1;
        }
    }
    __syncthreads();
    {
        int b = tid;
        int v = (b < NBUCK) ? cnt[b] : 0;
        int lane = tid & 63, wv = tid >> 6;
        int inc = v;
#pragma unroll
        for (int off = 1; off < 64; off <<= 1) {
            int u = __shfl_up(inc, off, 64);
            if (lane >= off) inc += u;
        }
        if (lane == 63) wtot[wv] = inc;
        __syncthreads();
        if (tid == 0) {
            int run = 0;
#pragma unroll
            for (int w = 0; w < 4; ++w) { woff[w] = run; run += wtot[w]; }
        }
        __syncthreads();
        int exc = woff[wv] + inc - v;
        if (b < NBUCK) {
            lstart[b] = exc;
            if (v > 0) gbase[b] = atomicAdd(&bucket_cursor[b], v);
        }
    }
    __syncthreads();
#pragma unroll
    for (int i = 0; i < 16; ++i) {
        if (bb[i] >= 0) {
            int p = lstart[bb[i]] + loff[i];
            lcv[p] = pcv[i];
            lbb[p] = (unsigned char)bb[i];
        }
    }
    __syncthreads();
    const int total = lstart[NBUCK - 1] + cnt[NBUCK - 1];
    for (int p = tid; p < total; p += 256) {
        int b = lbb[p];
        int g = gbase[b] + (p - lstart[b]);
        staging[g] = lcv[p];
    }
}

// ---------------- binned scatter pass 2: count+scan in LDS, emit rowrange --------
__global__ __launch_bounds__(256) void binpass2_kernel(const int* __restrict__ bucket_cursor,
                                                       const int2* __restrict__ staging,
                                                       int2* __restrict__ cedge,
                                                       int2* __restrict__ rowrange) {
    __shared__ int cnt[1 << BSHIFT];
    __shared__ int scur[1 << BSHIFT];
    __shared__ int wtot[4];
    __shared__ int woff[4];
    const int b   = blockIdx.x;
    const int tid = threadIdx.x;
    const int base = b * CAP;
    const int hi   = bucket_cursor[b];
    for (int i = tid; i < (1 << BSHIFT); i += 256) cnt[i] = 0;
    __syncthreads();
    for (int k = base + tid; k < hi; k += 256)
        atomicAdd(&cnt[((u32)staging[k].x) >> 17], 1);
    __syncthreads();
    int v0 = cnt[2 * tid];
    int v1 = cnt[2 * tid + 1];
    int s = v0 + v1;
    int lane = tid & 63, wv = tid >> 6;
    int inc = s;
#pragma unroll
    for (int off = 1; off < 64; off <<= 1) {
        int u = __shfl_up(inc, off, 64);
        if (lane >= off) inc += u;
    }
    if (lane == 63) wtot[wv] = inc;
    __syncthreads();
    if (tid == 0) {
        int run = 0;
#pragma unroll
        for (int w = 0; w < 4; ++w) { woff[w] = run; run += wtot[w]; }
    }
    __syncthreads();
    int exc = woff[wv] + inc - s;
    int g0 = base + exc;
    scur[2 * tid]     = g0;
    scur[2 * tid + 1] = g0 + v0;
    const int r0 = b << BSHIFT;
    int r = r0 + 2 * tid;
    if (r < N_NODES)     rowrange[r]     = make_int2(g0, g0 + v0);
    if (r + 1 < N_NODES) rowrange[r + 1] = make_int2(g0 + v0, g0 + v0 + v1);
    __syncthreads();
    for (int k = base + tid; k < hi; k += 256) {
        int2 e = staging[k];
        int rloc = ((u32)e.x) >> 17;
        int pos = atomicAdd(&scur[rloc], 1);
        cedge[pos] = make_int2(e.x & 0x1FFFF, e.y);
    }
}

// ---------------- f32 -> bf16 + fp8 (+ folded bucket-cursor init) ----------------
__global__ __launch_bounds__(256) void cvt_kernel(const float* __restrict__ in,
                                                  ushort* __restrict__ out, int n4,
                                                  int* __restrict__ bucket_cursor,
                                                  u32* __restrict__ outq) {
    int i = blockIdx.x * 256 + threadIdx.x;
    if (blockIdx.x == 0 && threadIdx.x < NBUCK)
        bucket_cursor[threadIdx.x] = threadIdx.x * CAP;  // runs before binpass1 (stream order)
    if (i < n4) {
        float4 v = ((const float4*)in)[i];
        uint2 p;
        p.x = (unsigned)f2b(v.x) | ((unsigned)f2b(v.y) << 16);
        p.y = (unsigned)f2b(v.z) | ((unsigned)f2b(v.w) << 16);
        ((uint2*)out)[i] = p;
        outq[i] = f32x4_to_fp8(v.x, v.y, v.z, v.w);
    }
}

// ---------------- W [512][256] f32 -> swizzled Wt bf16 ---------------------------
__global__ __launch_bounds__(256) void wtrans_kernel(const float* __restrict__ W1,
                                                     const float* __restrict__ Wout,
                                                     ushort* __restrict__ W1sz,
                                                     ushort* __restrict__ Woutsz) {
    int t = blockIdx.x * 256 + threadIdx.x;       // 0..262143
    const float* W = (t < 131072) ? W1 : Wout;
    ushort* Wsz    = (t < 131072) ? W1sz : Woutsz;
    int u = t & 131071;
    int j = u & 255;
    int k = u >> 8;
    int dst = j * 512 + ((((k >> 3) ^ (j & 63)) << 3) | (k & 7));
    Wsz[dst] = f2b(W[(size_t)k * 256 + j]);
}

// ---------------- CSR SpMM, fp8 gather, software-pipelined chunks ----------------
// Ping-pong two 8-edge register sets: while chunk A computes, chunk B's 8
// gathers are in flight -> memory stays saturated through the decode/FMA phase
// (R17's load8->compute8 serialized them; fill BW stalled at 3.05/3.5 TB/s).
__global__ __launch_bounds__(256) void spmm_kernel(const int2* __restrict__ rowrange,
                                                   const int2* __restrict__ cedge,
                                                   const unsigned char* __restrict__ hq,
                                                   ushort* __restrict__ outb) {
    const int node = (blockIdx.x << 2) + (threadIdx.x >> 6);
    const int lane = threadIdx.x & 63;
    const u32* __restrict__ h1 = (const u32*)hq + lane;  // row = 64 u32
    int2 rr = rowrange[node];
    int k = rr.x;
    const int end = rr.y;
    float a0 = 0.f, a1 = 0.f, a2 = 0.f, a3 = 0.f;
    int2 eA[8], eB[8];
    u32  dA[8], dB[8];
#define LOAD8(E, Dr, base)                                          \
    {                                                               \
        _Pragma("unroll")                                           \
        for (int i = 0; i < 8; ++i) (E)[i] = cedge[(base) + i];     \
        _Pragma("unroll")                                           \
        for (int i = 0; i < 8; ++i) (Dr)[i] = h1[(u32)(E)[i].x * 64]; \
    }
#define FMA1(e, d)                                                  \
    {                                                               \
        float v = __int_as_float((e).y);                            \
        float f[4];                                                 \
        fp8x4_to_f32((d), f);                                       \
        a0 = fmaf(v, f[0], a0); a1 = fmaf(v, f[1], a1);             \
        a2 = fmaf(v, f[2], a2); a3 = fmaf(v, f[3], a3);             \
    }
#define FMA8(E, Dr)                                                 \
    {                                                               \
        _Pragma("unroll")                                           \
        for (int i = 0; i < 8; ++i) FMA1((E)[i], (Dr)[i])           \
    }
    const int nfull = (end - k) >> 3;
    if (nfull > 0) {
        LOAD8(eA, dA, k)
        int c = 1;
        for (; c + 1 < nfull; c += 2) {
            LOAD8(eB, dB, k + c * 8)
            FMA8(eA, dA)
            LOAD8(eA, dA, k + (c + 1) * 8)
            FMA8(eB, dB)
        }
        if (c < nfull) {           // one more full chunk after A
            LOAD8(eB, dB, k + c * 8)
            FMA8(eA, dA)
            FMA8(eB, dB)
        } else {
            FMA8(eA, dA)
        }
        k += nfull << 3;
    }
    for (; k < end; ++k) {
        int2 e = cedge[k];
        u32 d = h1[(u32)e.x * 64];
        FMA1(e, d)
    }
#undef LOAD8
#undef FMA1
#undef FMA8
    uint2 p;
    p.x = (unsigned)f2b(a0) | ((unsigned)f2b(a1) << 16);
    p.y = (unsigned)f2b(a2) | ((unsigned)f2b(a3) << 16);
    ((uint2*)outb)[(size_t)node * 64 + lane] = p;
}

// ---------------- MFMA concat-GEMM: B-resident LDS, barrier-free K loop ----------
// OUT_BF16 epilogue additionally writes the fp8 copy of h1 (spmm2's gather table).
template <bool OUT_BF16>
__global__ __launch_bounds__(512, 2) void gemm_mfma_kernel(const ushort* __restrict__ A1,
                                                           const ushort* __restrict__ A2,
                                                           const ushort* __restrict__ Wsz,
                                                           const float* __restrict__ bias,
                                                           void* __restrict__ outp,
                                                           unsigned char* __restrict__ outq) {
    __shared__ __align__(16) char lds[163840];  // B 0..131071, A rings 131072..163839
    const int tid  = threadIdx.x;
    const int wid  = tid >> 6;                  // 0..7
    const int lane = tid & 63;
    const int lr   = lane & 15;
    const int g    = lane >> 4;
    const int bm   = blockIdx.x * 128;
    const int c0   = blockIdx.y * 128;
    char* const ldsA = lds + 131072 + wid * 4096;

    int arow = bm + wid * 16 + (lane >> 2);
    if (arow >= N_NODES) arow = N_NODES - 1;    // clamp; stores guarded
    const int acol = (lane & 3) * 8;

#define STAGE_A(tt)                                                              \
    {                                                                            \
        const ushort* As_ = ((tt) < 8) ? A1 : A2;                                \
        GLOAD16(As_ + (size_t)arow * 256 + ((tt) & 7) * 32 + acol,               \
                ldsA + ((tt) & 3) * 1024);                                       \
    }

    int jbyte[8], jx[8];
#pragma unroll
    for (int cf = 0; cf < 8; ++cf) {
        int jl = cf * 16 + lr;
        jbyte[cf] = jl * 1024;
        jx[cf] = jl & 63;
    }

#pragma unroll
    for (int q = 0; q < 16; ++q)
        GLOAD16(Wsz + (size_t)c0 * 512 + (wid * 16 + q) * 512 + lane * 8,
                lds + (wid * 16 + q) * 1024);
    STAGE_A(0)
    STAGE_A(1)
    STAGE_A(2)
    asm volatile("s_waitcnt vmcnt(2)" ::: "memory");  // B + A(0) done
    __builtin_amdgcn_sched_barrier(0);
    __builtin_amdgcn_s_barrier();                     // all waves' B slices ready

    f32x4 acc[8];
#pragma unroll
    for (int cf = 0; cf < 8; ++cf) acc[cf] = (f32x4){0.f, 0.f, 0.f, 0.f};

#pragma unroll 1
    for (int t = 0; t < 16; ++t) {
        if (t < 13) {
            STAGE_A(t + 3)
            asm volatile("s_waitcnt vmcnt(3)" ::: "memory");
        } else if (t == 13) {
            asm volatile("s_waitcnt vmcnt(2)" ::: "memory");
        } else if (t == 14) {
            asm volatile("s_waitcnt vmcnt(1)" ::: "memory");
        } else {
            asm volatile("s_waitcnt vmcnt(0)" ::: "memory");
        }
        __builtin_amdgcn_sched_barrier(0);
        const char* Ab = ldsA + (t & 3) * 1024;
        bf16x8 af = *(const bf16x8*)(Ab + lr * 64 + g * 16);
        const int cbase = t * 4 + g;  // k-chunk index 0..63
#pragma unroll
        for (int cf = 0; cf < 8; ++cf) {
            bf16x8 bf_ = *(const bf16x8*)(lds + jbyte[cf] + ((cbase ^ jx[cf]) << 4));
            acc[cf] = __builtin_amdgcn_mfma_f32_16x16x32_bf16(af, bf_, acc[cf], 0, 0, 0);
        }
    }
#undef STAGE_A

    float bv[8];
#pragma unroll
    for (int cf = 0; cf < 8; ++cf) bv[cf] = bias[c0 + cf * 16 + lr];

    if (!OUT_BF16) {
        float* out = (float*)outp;
#pragma unroll
        for (int reg = 0; reg < 4; ++reg) {
            int row = bm + wid * 16 + g * 4 + reg;
            if (row < N_NODES) {
#pragma unroll
                for (int cf = 0; cf < 8; ++cf)
                    out[(size_t)row * 256 + c0 + cf * 16 + lr] = acc[cf][reg] + bv[cf];
            }
        }
    } else {
        __builtin_amdgcn_s_barrier();             // all waves done reading B
        ushort* out = (ushort*)outp;
        float (*L)[132] = (float(*)[132])(lds + wid * 16384);
#pragma unroll
        for (int cf = 0; cf < 8; ++cf)
#pragma unroll
            for (int reg = 0; reg < 4; ++reg)
                L[g * 4 + reg][cf * 16 + lr] = fmaxf(acc[cf][reg] + bv[cf], 0.f);
    asm volatile("s_waitcnt lgkmcnt(0)" ::: "memory");
        __builtin_amdgcn_sched_barrier(0);
        const int r  = lane >> 2;                 // 0..15
        const int cq = lane & 3;
        const int grow = bm + wid * 16 + r;
        if (grow < N_NODES) {
#pragma unroll
            for (int q = 0; q < 4; ++q) {
                int col = q * 32 + cq * 8;
                float4 u0 = *(const float4*)&L[r][col];
                float4 u1 = *(const float4*)&L[r][col + 4];
                uint4 w4;
                w4.x = (unsigned)f2b(u0.x) | ((unsigned)f2b(u0.y) << 16);
                w4.y = (unsigned)f2b(u0.z) | ((unsigned)f2b(u0.w) << 16);
                w4.z = (unsigned)f2b(u1.x) | ((unsigned)f2b(u1.y) << 16);
                w4.w = (unsigned)f2b(u1.z) | ((unsigned)f2b(u1.w) << 16);
                *(uint4*)&out[(size_t)grow * 256 + c0 + col] = w4;
                uint2 q8;
                q8.x = f32x4_to_fp8(u0.x, u0.y, u0.z, u0.w);
                q8.y = f32x4_to_fp8(u1.x, u1.y, u1.z, u1.w);
                *(uint2*)&outq[(size_t)grow * 256 + c0 + col] = q8;
            }
        }
    }
}

extern "C" void kernel_launch(void* const* d_in, const int* in_sizes, int n_in,
                              void* d_out, int out_size, void* d_ws, size_t ws_size,
                              hipStream_t stream) {
    const float* x     = (const float*)d_in[0];
    const int*   erow  = (const int*)d_in[1];
    const int*   ecol  = (const int*)d_in[2];
    const float* evalv = (const float*)d_in[3];
    const float* W1    = (const float*)d_in[4];
    const float* b1    = (const float*)d_in[5];
    const float* Wout  = (const float*)d_in[6];
    const float* bout  = (const float*)d_in[7];
    float* out = (float*)d_out;

    char* ws = (char*)d_ws;
    size_t off = 0;
    auto alloc = [&](size_t bytes) -> void* {
        void* p = ws + off;
        off += (bytes + 255) & ~(size_t)255;
        return p;
    };
    ushort* xb       = (ushort*)alloc((size_t)N_NODES * D * 2);     // 51.2 MB
    ushort* h1b      = (ushort*)alloc((size_t)N_NODES * D * 2);     // 51.2 MB
    ushort* neighb   = (ushort*)alloc((size_t)N_NODES * D * 2);     // 51.2 MB
    unsigned char* xq  = (unsigned char*)alloc((size_t)N_NODES * D);  // 25.6 MB
    unsigned char* h1q = (unsigned char*)alloc((size_t)N_NODES * D);  // 25.6 MB
    ushort* W1sz     = (ushort*)alloc((size_t)512 * 256 * 2);
    ushort* Woutsz   = (ushort*)alloc((size_t)512 * 256 * 2);
    int*    bcursor  = (int*)alloc((size_t)NBUCK * sizeof(int));
    int2*   rowrange = (int2*)alloc((size_t)N_NODES * sizeof(int2));      // 0.8 MB
    int2*   staging  = (int2*)alloc((size_t)NBUCK * CAP * sizeof(int2));  // 32.1 MB
    int2*   cedge    = (int2*)alloc((size_t)NBUCK * CAP * sizeof(int2));  // 32.1 MB

    // converts first (cvt also initializes bcursor; stream order covers binpass1)
    cvt_kernel<<<(N_NODES * D / 4 + 255) / 256, 256, 0, stream>>>(x, xb, N_NODES * D / 4,
                                                                  bcursor, (u32*)xq);
    wtrans_kernel<<<1024, 256, 0, stream>>>(W1, Wout, W1sz, Woutsz);

    // CSR build
    binpass1_kernel<<<(N_EDGES + EPB - 1) / EPB, 256, 0, stream>>>(erow, ecol, evalv,
                                                                   bcursor, staging);
    binpass2_kernel<<<NBUCK, 256, 0, stream>>>(bcursor, staging, cedge, rowrange);

    dim3 ggrid((N_NODES + 127) / 128, 2);  // 782 x 2
    const int sgrid = N_NODES / 4;
    // layer 1 (gather from fp8 x; GEMM A-inputs stay bf16)
    spmm_kernel<<<sgrid, 256, 0, stream>>>(rowrange, cedge, xq, neighb);
    gemm_mfma_kernel<true><<<ggrid, 512, 0, stream>>>(xb, neighb, W1sz, b1, h1b, h1q);
    // layer 2 (gather from fp8 h1)
    spmm_kernel<<<sgrid, 256, 0, stream>>>(rowrange, cedge, h1q, neighb);
    gemm_mfma_kernel<false><<<ggrid, 512, 0, stream>>>(h1b, neighb, Woutsz, bout, out, nullptr);
}

// Round 19
// 467.033 us; speedup vs baseline: 1.5209x; 1.0241x over previous
//
#include <hip/hip_runtime.h>
#include <cstddef>
#include <cstdint>

#define N_NODES 100000
#define N_EDGES 3200000
#define D 256
#define BSHIFT 9                                // 512 rows per bucket
#define NBUCK ((N_NODES + (1 << BSHIFT) - 1) >> BSHIFT)  // 196
#define EPB 4096                                // edges per pass-1 block
#define CAP 20480                               // staging slots per bucket
#define NTILE ((N_NODES + 127) / 128)           // 782 row tiles

typedef __attribute__((ext_vector_type(8))) short bf16x8;
typedef __attribute__((ext_vector_type(4))) float f32x4;
typedef __attribute__((ext_vector_type(2))) float f32x2;
typedef unsigned int u32;

#if defined(__has_builtin)
#if __has_builtin(__builtin_amdgcn_cvt_pk_f32_fp8) && __has_builtin(__builtin_amdgcn_cvt_pk_fp8_f32)
#define FP8_BUILTINS 1
#endif
#endif
#ifndef FP8_BUILTINS
#include <hip/hip_fp8.h>
#endif

__device__ __forceinline__ void fp8x4_to_f32(u32 d, float* f) {
#ifdef FP8_BUILTINS
    f32x2 lo = __builtin_amdgcn_cvt_pk_f32_fp8(d, false);
    f32x2 hi = __builtin_amdgcn_cvt_pk_f32_fp8(d, true);
    f[0] = lo.x; f[1] = lo.y; f[2] = hi.x; f[3] = hi.y;
#else
    __hip_fp8_e4m3 t;
#pragma unroll
    for (int i = 0; i < 4; ++i) { t.__x = (unsigned char)((d >> (8 * i)) & 0xff); f[i] = (float)t; }
#endif
}

__device__ __forceinline__ u32 f32x4_to_fp8(float a, float b, float c, float d) {
#ifdef FP8_BUILTINS
    u32 q = __builtin_amdgcn_cvt_pk_fp8_f32(a, b, 0u, false);
    return __builtin_amdgcn_cvt_pk_fp8_f32(c, d, q, true);
#else
    return (u32)__hip_fp8_e4m3(a).__x | ((u32)__hip_fp8_e4m3(b).__x << 8) |
           ((u32)__hip_fp8_e4m3(c).__x << 16) | ((u32)__hip_fp8_e4m3(d).__x << 24);
#endif
}

#define GLOAD16(gsrc, ldst)                                                      \
    __builtin_amdgcn_global_load_lds(                                            \
        (const __attribute__((address_space(1))) void*)(gsrc),                   \
        (__attribute__((address_space(3))) void*)(ldst), 16, 0, 0)

__device__ __forceinline__ ushort f2b(float f) {  // f32 -> bf16 RNE
    unsigned u = __float_as_uint(f);
    return (ushort)((u + 0x7fffu + ((u >> 16) & 1u)) >> 16);
}

// ---------------- binned scatter pass 1 ----------------
__global__ __launch_bounds__(256) void binpass1_kernel(const int* __restrict__ erow,
                                                       const int* __restrict__ ecol,
                                                       const float* __restrict__ evalv,
                                                       int* __restrict__ bucket_cursor,
                                                       int2* __restrict__ staging) {
    __shared__ int cnt[NBUCK];
    __shared__ int lstart[NBUCK];
    __shared__ int gbase[NBUCK];
    __shared__ int wtot[4];
    __shared__ int woff[4];
    __shared__ int2 lcv[EPB];            // 32 KB
    __shared__ unsigned char lbb[EPB];   // 4 KB
    const int tid = threadIdx.x;
    const size_t base = (size_t)blockIdx.x * EPB;
    for (int b = tid; b < NBUCK; b += 256) cnt[b] = 0;
    __syncthreads();
    int bb[16];
    int2 pcv[16];
    int loff[16];
#pragma unroll
    for (int i = 0; i < 16; ++i) {
        size_t e = base + (size_t)i * 256 + tid;
        if (e < N_EDGES) {
            int r = erow[e];
            int b = r >> BSHIFT;
            bb[i] = b;
            pcv[i] = make_int2(ecol[e] | ((r & ((1 << BSHIFT) - 1)) << 17),
                               __float_as_int(evalv[e]));
            loff[i] = atomicAdd(&cnt[b], 1);
        } else {
            bb[i] = -1;
        }
    }
    __syncthreads();
    {
        int b = tid;
        int v = (b < NBUCK) ? cnt[b] : 0;
        int lane = tid & 63, wv = tid >> 6;
        int inc = v;
#pragma unroll
        for (int off = 1; off < 64; off <<= 1) {
            int u = __shfl_up(inc, off, 64);
            if (lane >= off) inc += u;
        }
        if (lane == 63) wtot[wv] = inc;
        __syncthreads();
        if (tid == 0) {
            int run = 0;
#pragma unroll
            for (int w = 0; w < 4; ++w) { woff[w] = run; run += wtot[w]; }
        }
        __syncthreads();
        int exc = woff[wv] + inc - v;
        if (b < NBUCK) {
            lstart[b] = exc;
            if (v > 0) gbase[b] = atomicAdd(&bucket_cursor[b], v);
        }
    }
    __syncthreads();
#pragma unroll
    for (int i = 0; i < 16; ++i) {
        if (bb[i] >= 0) {
            int p = lstart[bb[i]] + loff[i];
            lcv[p] = pcv[i];
            lbb[p] = (unsigned char)bb[i];
        }
    }
    __syncthreads();
    const int total = lstart[NBUCK - 1] + cnt[NBUCK - 1];
    for (int p = tid; p < total; p += 256) {
        int b = lbb[p];
        int g = gbase[b] + (p - lstart[b]);
        staging[g] = lcv[p];
    }
}

// ---------------- binned scatter pass 2: count+scan in LDS, emit rowrange --------
__global__ __launch_bounds__(256) void binpass2_kernel(const int* __restrict__ bucket_cursor,
                                                       const int2* __restrict__ staging,
                                                       int2* __restrict__ cedge,
                                                       int2* __restrict__ rowrange) {
    __shared__ int cnt[1 << BSHIFT];
    __shared__ int scur[1 << BSHIFT];
    __shared__ int wtot[4];
    __shared__ int woff[4];
    const int b   = blockIdx.x;
    const int tid = threadIdx.x;
    const int base = b * CAP;
    const int hi   = bucket_cursor[b];
    for (int i = tid; i < (1 << BSHIFT); i += 256) cnt[i] = 0;
    __syncthreads();
    for (int k = base + tid; k < hi; k += 256)
        atomicAdd(&cnt[((u32)staging[k].x) >> 17], 1);
    __syncthreads();
    int v0 = cnt[2 * tid];
    int v1 = cnt[2 * tid + 1];
    int s = v0 + v1;
    int lane = tid & 63, wv = tid >> 6;
    int inc = s;
#pragma unroll
    for (int off = 1; off < 64; off <<= 1) {
        int u = __shfl_up(inc, off, 64);
        if (lane >= off) inc += u;
    }
    if (lane == 63) wtot[wv] = inc;
    __syncthreads();
    if (tid == 0) {
        int run = 0;
#pragma unroll
        for (int w = 0; w < 4; ++w) { woff[w] = run; run += wtot[w]; }
    }
    __syncthreads();
    int exc = woff[wv] + inc - s;
    int g0 = base + exc;
    scur[2 * tid]     = g0;
    scur[2 * tid + 1] = g0 + v0;
    const int r0 = b << BSHIFT;
    int r = r0 + 2 * tid;
    if (r < N_NODES)     rowrange[r]     = make_int2(g0, g0 + v0);
    if (r + 1 < N_NODES) rowrange[r + 1] = make_int2(g0 + v0, g0 + v0 + v1);
    __syncthreads();
    for (int k = base + tid; k < hi; k += 256) {
        int2 e = staging[k];
        int rloc = ((u32)e.x) >> 17;
        int pos = atomicAdd(&scur[rloc], 1);
        cedge[pos] = make_int2(e.x & 0x1FFFF, e.y);
    }
}

// ---------------- f32 -> bf16 + fp8 (+ folded bucket-cursor init) ----------------
__global__ __launch_bounds__(256) void cvt_kernel(const float* __restrict__ in,
                                                  ushort* __restrict__ out, int n4,
                                                  int* __restrict__ bucket_cursor,
                                                  u32* __restrict__ outq) {
    int i = blockIdx.x * 256 + threadIdx.x;
    if (blockIdx.x == 0 && threadIdx.x < NBUCK)
        bucket_cursor[threadIdx.x] = threadIdx.x * CAP;  // runs before binpass1 (stream order)
    if (i < n4) {
        float4 v = ((const float4*)in)[i];
        uint2 p;
        p.x = (unsigned)f2b(v.x) | ((unsigned)f2b(v.y) << 16);
        p.y = (unsigned)f2b(v.z) | ((unsigned)f2b(v.w) << 16);
        ((uint2*)out)[i] = p;
        outq[i] = f32x4_to_fp8(v.x, v.y, v.z, v.w);
    }
}

// ---------------- W [512][256] f32 -> swizzled Wt bf16 ---------------------------
__global__ __launch_bounds__(256) void wtrans_kernel(const float* __restrict__ W1,
                                                     const float* __restrict__ Wout,
                                                     ushort* __restrict__ W1sz,
                                                     ushort* __restrict__ Woutsz) {
    int t = blockIdx.x * 256 + threadIdx.x;       // 0..262143
    const float* W = (t < 131072) ? W1 : Wout;
    ushort* Wsz    = (t < 131072) ? W1sz : Woutsz;
    int u = t & 131071;
    int j = u & 255;
    int k = u >> 8;
    int dst = j * 512 + ((((k >> 3) ^ (j & 63)) << 3) | (k & 7));
    Wsz[dst] = f2b(W[(size_t)k * 256 + j]);
}

// ---------------- CSR SpMM, fp8 gather table: one wave per node, unroll 8 --------
// At its measured structural floor: random 256B-granule fills cap at ~3.0 TB/s
// (R14/R16/R17/R18 all converge here). Simple unroll-8 form (R17).
__global__ __launch_bounds__(256) void spmm_kernel(const int2* __restrict__ rowrange,
                                                   const int2* __restrict__ cedge,
                                                   const unsigned char* __restrict__ hq,
                                                   ushort* __restrict__ outb) {
    const int node = (blockIdx.x << 2) + (threadIdx.x >> 6);
    const int lane = threadIdx.x & 63;
    const u32* __restrict__ h1 = (const u32*)hq + lane;  // row = 64 u32
    int2 rr = rowrange[node];
    int k = rr.x;
    const int end = rr.y;
    float a0 = 0.f, a1 = 0.f, a2 = 0.f, a3 = 0.f;
#define EDGE_FMA(e, d)                                              \
    {                                                               \
        float v = __int_as_float((e).y);                            \
        float f[4];                                                 \
        fp8x4_to_f32((d), f);                                       \
        a0 = fmaf(v, f[0], a0); a1 = fmaf(v, f[1], a1);             \
        a2 = fmaf(v, f[2], a2); a3 = fmaf(v, f[3], a3);             \
    }
    for (; k + 8 <= end; k += 8) {
        int2 e[8];
#pragma unroll
        for (int i = 0; i < 8; ++i) e[i] = cedge[k + i];
        u32 d[8];
#pragma unroll
        for (int i = 0; i < 8; ++i) d[i] = h1[(u32)e[i].x * 64];
#pragma unroll
        for (int i = 0; i < 8; ++i) EDGE_FMA(e[i], d[i])
    }
    for (; k < end; ++k) {
        int2 e = cedge[k];
        u32 d = h1[(u32)e.x * 64];
        EDGE_FMA(e, d)
    }
#undef EDGE_FMA
    uint2 p;
    p.x = (unsigned)f2b(a0) | ((unsigned)f2b(a1) << 16);
    p.y = (unsigned)f2b(a2) | ((unsigned)f2b(a3) << 16);
    ((uint2*)outb)[(size_t)node * 64 + lane] = p;
}

// ---------------- MFMA concat-GEMM: PERSISTENT B-resident blocks -----------------
// 512 blocks (1 resident/CU, 2 sequential), 512 threads. Each block loads its
// 128KB B-half ONCE, then loops over row tiles (tile = pairId + 256*i): A-ring
// pipeline + MFMA + epilogue, no barriers after the initial B barrier.
// gemm1 (OUT_BF16) epilogue uses the wave's PRIVATE 4KB A-ring as repack
// scratch (two 8-row passes, lgkmcnt-only) so B is never clobbered.
// vmcnt counted waits remain valid with interleaved stores (FIFO retirement).
template <bool OUT_BF16>
__global__ __launch_bounds__(512, 1) void gemm_mfma_kernel(const ushort* __restrict__ A1,
                                                           const ushort* __restrict__ A2,
                                                           const ushort* __restrict__ Wsz,
                                                           const float* __restrict__ bias,
                                                           void* __restrict__ outp,
                                                           unsigned char* __restrict__ outq) {
    __shared__ __align__(16) char lds[163840];  // B 0..131071, A rings 131072..163839
    const int tid  = threadIdx.x;
    const int wid  = tid >> 6;                  // 0..7
    const int lane = tid & 63;
    const int lr   = lane & 15;
    const int g    = lane >> 4;
    const int c0     = (blockIdx.x & 1) * 128;
    const int pairId = blockIdx.x >> 1;         // 0..255
    char* const ldsA = lds + 131072 + wid * 4096;
    const int acol = (lane & 3) * 8;

    // B half (16 x 1KB per wave, linear) -- ONCE per block
#pragma unroll
    for (int q = 0; q < 16; ++q)
        GLOAD16(Wsz + (size_t)c0 * 512 + (wid * 16 + q) * 512 + lane * 8,
                lds + (wid * 16 + q) * 1024);
    float bv[8];
#pragma unroll
    for (int cf = 0; cf < 8; ++cf) bv[cf] = bias[c0 + cf * 16 + lr];
    int jbyte[8], jx[8];
#pragma unroll
    for (int cf = 0; cf < 8; ++cf) {
        int jl = cf * 16 + lr;
        jbyte[cf] = jl * 1024;
        jx[cf] = jl & 63;
    }
    asm volatile("s_waitcnt vmcnt(0)" ::: "memory");
    __builtin_amdgcn_sched_barrier(0);
    __builtin_amdgcn_s_barrier();               // all waves' B slices ready

    int arow;
#define STAGE_A(tt)                                                              \
    {                                                                            \
        const ushort* As_ = ((tt) < 8) ? A1 : A2;                                \
        GLOAD16(As_ + (size_t)arow * 256 + ((tt) & 7) * 32 + acol,               \
                ldsA + ((tt) & 3) * 1024);                                       \
    }

#pragma unroll 1
    for (int tile = pairId; tile < NTILE; tile += 256) {
        const int bm = tile * 128;
        arow = bm + wid * 16 + (lane >> 2);
        if (arow >= N_NODES) arow = N_NODES - 1;  // clamp; stores guarded
        STAGE_A(0)
        STAGE_A(1)
        STAGE_A(2)

        f32x4 acc[8];
#pragma unroll
        for (int cf = 0; cf < 8; ++cf) acc[cf] = (f32x4){0.f, 0.f, 0.f, 0.f};

#pragma unroll 1
        for (int t = 0; t < 16; ++t) {
            if (t < 13) {
                STAGE_A(t + 3)
                asm volatile("s_waitcnt vmcnt(3)" ::: "memory");
            } else if (t == 13) {
                asm volatile("s_waitcnt vmcnt(2)" ::: "memory");
            } else if (t == 14) {
                asm volatile("s_waitcnt vmcnt(1)" ::: "memory");
            } else {
                asm volatile("s_waitcnt vmcnt(0)" ::: "memory");
            }
            __builtin_amdgcn_sched_barrier(0);
            const char* Ab = ldsA + (t & 3) * 1024;
            bf16x8 af = *(const bf16x8*)(Ab + lr * 64 + g * 16);
            const int cbase = t * 4 + g;  // k-chunk index 0..63
#pragma unroll
            for (int cf = 0; cf < 8; ++cf) {
                bf16x8 bf_ = *(const bf16x8*)(lds + jbyte[cf] + ((cbase ^ jx[cf]) << 4));
                acc[cf] = __builtin_amdgcn_mfma_f32_16x16x32_bf16(af, bf_, acc[cf], 0, 0, 0);
            }
        }

        if (!OUT_BF16) {
            // direct f32 stores (64B segments per 16-lane group)
            float* out = (float*)outp;
#pragma unroll
            for (int reg = 0; reg < 4; ++reg) {
                int row = bm + wid * 16 + g * 4 + reg;
                if (row < N_NODES) {
#pragma unroll
                    for (int cf = 0; cf < 8; ++cf)
                        out[(size_t)row * 256 + c0 + cf * 16 + lr] = acc[cf][reg] + bv[cf];
                }
            }
        } else {
            // relu + bf16/fp8 pack via wave-PRIVATE A-ring scratch (B untouched)
            ushort* out = (ushort*)outp;
            float (*L8)[128] = (float(*)[128])ldsA;  // 8 x 128 f32 = 4KB
#pragma unroll 1
            for (int half = 0; half < 2; ++half) {
                if ((g >> 1) == half) {
#pragma unroll
                    for (int cf = 0; cf < 8; ++cf)
#pragma unroll
                        for (int reg = 0; reg < 4; ++reg)
                            L8[(g & 1) * 4 + reg][cf * 16 + lr] =
                                fmaxf(acc[cf][reg] + bv[cf], 0.f);
                }
                asm volatile("s_waitcnt lgkmcnt(0)" ::: "memory");
                __builtin_amdgcn_sched_barrier(0);
                const int row8 = lane >> 3;
                const int cb = (lane & 7) * 16;
                const int grow = bm + wid * 16 + half * 8 + row8;
                if (grow < N_NODES) {
                    float4 u0 = *(const float4*)&L8[row8][cb];
                    float4 u1 = *(const float4*)&L8[row8][cb + 4];
                    float4 u2 = *(const float4*)&L8[row8][cb + 8];
                    float4 u3 = *(const float4*)&L8[row8][cb + 12];
                    uint4 w0, w1;
                    w0.x = (unsigned)f2b(u0.x) | ((unsigned)f2b(u0.y) << 16);
                    w0.y = (unsigned)f2b(u0.z) | ((unsigned)f2b(u0.w) << 16);
                    w0.z = (unsigned)f2b(u1.x) | ((unsigned)f2b(u1.y) << 16);
                    w0.w = (unsigned)f2b(u1.z) | ((unsigned)f2b(u1.w) << 16);
                    w1.x = (unsigned)f2b(u2.x) | ((unsigned)f2b(u2.y) << 16);
                    w1.y = (unsigned)f2b(u2.z) | ((unsigned)f2b(u2.w) << 16);
                    w1.z = (unsigned)f2b(u3.x) | ((unsigned)f2b(u3.y) << 16);
                    w1.w = (unsigned)f2b(u3.z) | ((unsigned)f2b(u3.w) << 16);
                    *(uint4*)&out[(size_t)grow * 256 + c0 + cb]     = w0;
                    *(uint4*)&out[(size_t)grow * 256 + c0 + cb + 8] = w1;
                    uint4 q8;
                    q8.x = f32x4_to_fp8(u0.x, u0.y, u0.z, u0.w);
                    q8.y = f32x4_to_fp8(u1.x, u1.y, u1.z, u1.w);
                    q8.z = f32x4_to_fp8(u2.x, u2.y, u2.z, u2.w);
                    q8.w = f32x4_to_fp8(u3.x, u3.y, u3.z, u3.w);
                    *(uint4*)&outq[(size_t)grow * 256 + c0 + cb] = q8;
                }
                asm volatile("s_waitcnt lgkmcnt(0)" ::: "memory");  // reads done before
                __builtin_amdgcn_sched_barrier(0);                  // next half / STAGE_A
            }
        }
    }
#undef STAGE_A
}

extern "C" void kernel_launch(void* const* d_in, const int* in_sizes, int n_in,
                              void* d_out, int out_size, void* d_ws, size_t ws_size,
                              hipStream_t stream) {
    const float* x     = (const float*)d_in[0];
    const int*   erow  = (const int*)d_in[1];
    const int*   ecol  = (const int*)d_in[2];
    const float* evalv = (const float*)d_in[3];
    const float* W1    = (const float*)d_in[4];
    const float* b1    = (const float*)d_in[5];
    const float* Wout  = (const float*)d_in[6];
    const float* bout  = (const float*)d_in[7];
    float* out = (float*)d_out;

    char* ws = (char*)d_ws;
    size_t off = 0;
    auto alloc = [&](size_t bytes) -> void* {
        void* p = ws + off;
        off += (bytes + 255) & ~(size_t)255;
        return p;
    };
    ushort* xb       = (ushort*)alloc((size_t)N_NODES * D * 2);     // 51.2 MB
    ushort* h1b      = (ushort*)alloc((size_t)N_NODES * D * 2);     // 51.2 MB
    ushort* neighb   = (ushort*)alloc((size_t)N_NODES * D * 2);     // 51.2 MB
    unsigned char* xq  = (unsigned char*)alloc((size_t)N_NODES * D);  // 25.6 MB
    unsigned char* h1q = (unsigned char*)alloc((size_t)N_NODES * D);  // 25.6 MB
    ushort* W1sz     = (ushort*)alloc((size_t)512 * 256 * 2);
    ushort* Woutsz   = (ushort*)alloc((size_t)512 * 256 * 2);
    int*    bcursor  = (int*)alloc((size_t)NBUCK * sizeof(int));
    int2*   rowrange = (int2*)alloc((size_t)N_NODES * sizeof(int2));      // 0.8 MB
    int2*   staging  = (int2*)alloc((size_t)NBUCK * CAP * sizeof(int2));  // 32.1 MB
    int2*   cedge    = (int2*)alloc((size_t)NBUCK * CAP * sizeof(int2));  // 32.1 MB

    // converts first (cvt also initializes bcursor; stream order covers binpass1)
    cvt_kernel<<<(N_NODES * D / 4 + 255) / 256, 256, 0, stream>>>(x, xb, N_NODES * D / 4,
                                                                  bcursor, (u32*)xq);
    wtrans_kernel<<<1024, 256, 0, stream>>>(W1, Wout, W1sz, Woutsz);

    // CSR build
    binpass1_kernel<<<(N_EDGES + EPB - 1) / EPB, 256, 0, stream>>>(erow, ecol, evalv,
                                                                   bcursor, staging);
    binpass2_kernel<<<NBUCK, 256, 0, stream>>>(bcursor, staging, cedge, rowrange);

    const int sgrid = N_NODES / 4;
    // layer 1 (gather from fp8 x; GEMM A-inputs stay bf16)
    spmm_kernel<<<sgrid, 256, 0, stream>>>(rowrange, cedge, xq, neighb);
    gemm_mfma_kernel<true><<<512, 512, 0, stream>>>(xb, neighb, W1sz, b1, h1b, h1q);
    // layer 2 (gather from fp8 h1)
    spmm_kernel<<<sgrid, 256, 0, stream>>>(rowrange, cedge, h1q, neighb);
    gemm_mfma_kernel<false><<<512, 512, 0, stream>>>(h1b, neighb, Woutsz, bout, out, nullptr);
}